// Round 8
// baseline (735.732 us; speedup 1.0000x reference)
//
#include <hip/hip_runtime.h>

#define HD 128

typedef __attribute__((ext_vector_type(8))) short bf16x8;
typedef __attribute__((ext_vector_type(4))) float f32x4;

// ---- bf16 helpers ----------------------------------------------------------
__device__ __forceinline__ unsigned rne16(float x) {
  unsigned u = __builtin_bit_cast(unsigned, x);
  return (u + 0x7fffu + ((u >> 16) & 1u)) >> 16;
}
__device__ __forceinline__ unsigned pk2(float a, float b) {  // HW v_cvt_pk_bf16_f32
  unsigned r;
  asm("v_cvt_pk_bf16_f32 %0, %1, %2" : "=v"(r) : "v"(a), "v"(b));
  return r;
}
__device__ __forceinline__ float blo(unsigned u) { return __builtin_bit_cast(float, u << 16); }
__device__ __forceinline__ float bhi(unsigned u) { return __builtin_bit_cast(float, u & 0xffff0000u); }
__device__ __forceinline__ float bval(unsigned h16) { return __builtin_bit_cast(float, h16 << 16); }

__device__ __forceinline__ void bsplit(float v, unsigned short& hi, unsigned short& lo) {
  unsigned h = rne16(v);
  hi = (unsigned short)h;
  lo = (unsigned short)rne16(v - bval(h));
}
// pairwise split using HW pack
__device__ __forceinline__ void bsplit2(float v0, float v1, unsigned& hi, unsigned& lo) {
  hi = pk2(v0, v1);
  lo = pk2(v0 - bval(hi & 0xffffu), v1 - bval(hi >> 16));
}

// ---- degree count ----------------------------------------------------------
__global__ void count_k(const int* __restrict__ ei, int* __restrict__ cnt, int E) {
  int e = blockIdx.x * 256 + threadIdx.x;
  if (e < E) atomicAdd(&cnt[ei[E + e]], 1);
}

// ---- 3-phase multi-block exclusive scan ------------------------------------
__global__ __launch_bounds__(512) void scanA_k(const int* __restrict__ cnt,
                                               int* __restrict__ bsum, int n) {
  __shared__ int ws[8];
  const int tid = threadIdx.x, lane = tid & 63, wid = tid >> 6;
  int i = blockIdx.x * 512 + tid;
  int v = (i < n) ? cnt[i] : 0;
#pragma unroll
  for (int off = 32; off > 0; off >>= 1) v += __shfl_xor(v, off);
  if (lane == 0) ws[wid] = v;
  __syncthreads();
  if (tid == 0) {
    int s = 0;
#pragma unroll
    for (int w = 0; w < 8; ++w) s += ws[w];
    bsum[blockIdx.x] = s;
  }
}

__global__ __launch_bounds__(128) void scanB_k(int* __restrict__ bsum, int nb) {
  __shared__ int w2[2];
  const int tid = threadIdx.x, lane = tid & 63, wid = tid >> 6;
  int v = (tid < nb) ? bsum[tid] : 0;
  int s = v;
#pragma unroll
  for (int off = 1; off < 64; off <<= 1) {
    int u = __shfl_up(s, off);
    if (lane >= off) s += u;
  }
  if (lane == 63) w2[wid] = s;
  __syncthreads();
  int add = (wid == 1) ? w2[0] : 0;
  if (tid < nb) bsum[tid] = s - v + add;
}

__global__ __launch_bounds__(512) void scanC_k(int* __restrict__ cnt, float* __restrict__ invd,
                                               const int* __restrict__ bsum, int n) {
  __shared__ int ws[8];
  const int tid = threadIdx.x, lane = tid & 63, wid = tid >> 6;
  int i = blockIdx.x * 512 + tid;
  int v = (i < n) ? cnt[i] : 0;
  int s = v;
#pragma unroll
  for (int off = 1; off < 64; off <<= 1) {
    int u = __shfl_up(s, off);
    if (lane >= off) s += u;
  }
  if (lane == 63) ws[wid] = s;
  __syncthreads();
  int wadd = 0;
  for (int w = 0; w < wid; ++w) wadd += ws[w];
  if (i < n) {
    cnt[i] = s - v + wadd + bsum[blockIdx.x];
    invd[i] = v > 0 ? 1.f / (float)v : 0.f;
  }
}

// ---- scatter into dst-sorted order: spk[p] = src | (dst<<16) ---------------
__global__ void scatter_k(const int* __restrict__ ei, int* __restrict__ cur,
                          unsigned int* __restrict__ spk, int E) {
  int e = blockIdx.x * 256 + threadIdx.x;
  if (e >= E) return;
  int s = ei[e], d = ei[E + e];
  int p = atomicAdd(&cur[d], 1);
  spk[p] = (unsigned int)s | ((unsigned int)d << 16);
}

// ---- weight folding --------------------------------------------------------
__global__ void fold_all_k(const float* __restrict__ m3w2, const float* __restrict__ m2w1,
                           const float* __restrict__ m3b2, const float* __restrict__ m2b1,
                           const float* __restrict__ m2w2, const float* __restrict__ m1w1,
                           const float* __restrict__ m2b2,
                           float* __restrict__ Wf, float* __restrict__ ub,
                           float* __restrict__ Wm, float* __restrict__ bf) {
  const int k = blockIdx.x, l = blockIdx.y, mode = blockIdx.z, c = threadIdx.x;
  const float *A, *B, *bA, *badd;
  float *O, *ob;
  if (mode == 0) {
    A = m3w2 + (size_t)l * 128 * 128;
    B = m2w1 + (size_t)l * 256 * 128 + 128 * 128;
    bA = m3b2 + (size_t)l * 128; badd = m2b1 + (size_t)l * 128;
    O = Wf + (size_t)l * 128 * 128; ob = ub + (size_t)l * 128;
  } else {
    A = m2w2 + (size_t)l * 128 * 128;
    B = m1w1 + (size_t)l * 256 * 128;
    bA = m2b2 + (size_t)l * 128; badd = nullptr;
    O = Wm + (size_t)l * 128 * 128; ob = bf + (size_t)l * 128;
  }
  float s = 0.f;
  for (int r = 0; r < 128; ++r) s = fmaf(A[k * 128 + r], B[r * 128 + c], s);
  O[k * 128 + c] = s;
  if (k == 0) {
    float t = badd ? badd[c] : 0.f;
    for (int r = 0; r < 128; ++r) t = fmaf(bA[r], B[r * 128 + c], t);
    ob[c] = t;
  }
}

// ---- pack Wf into bf16 MFMA B-fragment order (edge kernel, hi only) --------
__global__ void pack_k(const float* __restrict__ Wf, unsigned short* __restrict__ Wpk) {
  int l = blockIdx.y;
  int flat = blockIdx.x * 256 + threadIdx.x;
  int e = flat & 7, l6 = (flat >> 3) & 63, ct = (flat >> 9) & 7, kt = flat >> 12;
  int row = kt * 32 + ((l6 >> 4) << 3) + e;
  int col = ct * 16 + (l6 & 15);
  Wpk[(size_t)l * 16384 + flat] =
      (unsigned short)rne16(Wf[(size_t)l * 16384 + row * 128 + col]);
}

// ---- pack node-GEMM weights into hi/lo B-fragment buffers ------------------
struct PDesc { const float* w0; const float* w1; unsigned short* out; int kt; };
struct PArgs { PDesc d[10]; };

__global__ void packw_k(PArgs pa) {
  PDesc de = pa.d[blockIdx.y];
  int flat = blockIdx.x * 256 + threadIdx.x;
  int tot = de.kt * 4096;
  if (flat >= tot) return;
  int e = flat & 7, ln = (flat >> 3) & 63, ct = (flat >> 9) & 7, kt = flat >> 12;
  int row = kt * 32 + ((ln >> 4) << 3) + e;
  int col = ct * 16 + (ln & 15);
  float v = (row < 128) ? de.w0[(size_t)row * 128 + col]
                        : de.w1[(size_t)(row - 128) * 128 + col];
  unsigned short hi, lo;
  bsplit(v, hi, lo);
  de.out[flat] = hi;
  de.out[tot + flat] = lo;
}

// ---- node GEMM via MFMA, hi/lo split ---------------------------------------
// A sources: AINIT -> relu(x*aw+ab); SPLIT0 -> in0h/in0l planes;
//            else f32 in0 (opt SCALE0 by sc); KT==8 upper half -> in1h/in1l.
// OUTMODE: 1 = bf16 hi only, 2 = hi/lo planes
template<int KT, bool RELU, bool SCALE0, bool BIAS2, bool SPLIT0, int OUTMODE, bool AINIT>
__global__ __launch_bounds__(256) void gemm_mfma(
    const float* __restrict__ in0f,
    const unsigned short* __restrict__ in0h, const unsigned short* __restrict__ in0l,
    const unsigned short* __restrict__ in1h, const unsigned short* __restrict__ in1l,
    const float* __restrict__ sc, const unsigned short* __restrict__ Wn,
    const float* __restrict__ bias, const float* __restrict__ bias2,
    const float* __restrict__ aw, const float* __restrict__ ab,
    unsigned short* __restrict__ outh, unsigned short* __restrict__ outl, int M)
{
  const int tid = threadIdx.x;
  const int lane = tid & 63, w4 = tid >> 6;
  const int lrow = lane & 15, lk = lane >> 4;
  const int m0 = blockIdx.x * 128;
  const unsigned short* __restrict__ Wlo = Wn + KT * 4096;

  int rown[2];
  bool valid[2];
  float scl[2], xv[2];
#pragma unroll
  for (int rt = 0; rt < 2; ++rt) {
    rown[rt] = m0 + w4 * 32 + rt * 16 + lrow;
    valid[rt] = rown[rt] < M;
    scl[rt] = (SCALE0 && valid[rt]) ? sc[rown[rt]] : 1.f;
    xv[rt] = (AINIT && valid[rt]) ? in0f[rown[rt]] : 0.f;
  }

  f32x4 acc[2][8];
#pragma unroll
  for (int rt = 0; rt < 2; ++rt)
#pragma unroll
    for (int ct = 0; ct < 8; ++ct) acc[rt][ct] = (f32x4){0.f, 0.f, 0.f, 0.f};

#pragma unroll
  for (int ktg = 0; ktg < KT; ++ktg) {
    const int k0 = ktg * 32 + lk * 8;
    bf16x8 ah[2], al[2];
    if (AINIT) {
      float4 a0 = *(const float4*)&aw[k0];
      float4 a1 = *(const float4*)&aw[k0 + 4];
      float4 b0 = *(const float4*)&ab[k0];
      float4 b1 = *(const float4*)&ab[k0 + 4];
      float awv[8] = {a0.x,a0.y,a0.z,a0.w,a1.x,a1.y,a1.z,a1.w};
      float abv[8] = {b0.x,b0.y,b0.z,b0.w,b1.x,b1.y,b1.z,b1.w};
#pragma unroll
      for (int rt = 0; rt < 2; ++rt) {
        unsigned h4[4], l4[4];
#pragma unroll
        for (int e = 0; e < 4; ++e) {
          float v0 = fmaf(xv[rt], awv[e*2], abv[e*2]);
          float v1 = fmaf(xv[rt], awv[e*2+1], abv[e*2+1]);
          v0 = v0 > 0.f ? v0 : 0.f;
          v1 = v1 > 0.f ? v1 : 0.f;
          bsplit2(v0, v1, h4[e], l4[e]);
        }
        ah[rt] = __builtin_bit_cast(bf16x8, *(uint4*)h4);
        al[rt] = __builtin_bit_cast(bf16x8, *(uint4*)l4);
      }
    } else if (KT == 8 && k0 >= 128) {
#pragma unroll
      for (int rt = 0; rt < 2; ++rt) {
        if (valid[rt]) {
          ah[rt] = *(const bf16x8*)&in1h[(size_t)rown[rt] * HD + (k0 - 128)];
          al[rt] = *(const bf16x8*)&in1l[(size_t)rown[rt] * HD + (k0 - 128)];
        } else {
          ah[rt] = (bf16x8){0,0,0,0,0,0,0,0};
          al[rt] = (bf16x8){0,0,0,0,0,0,0,0};
        }
      }
    } else if (SPLIT0) {
#pragma unroll
      for (int rt = 0; rt < 2; ++rt) {
        if (valid[rt]) {
          ah[rt] = *(const bf16x8*)&in0h[(size_t)rown[rt] * HD + k0];
          al[rt] = *(const bf16x8*)&in0l[(size_t)rown[rt] * HD + k0];
        } else {
          ah[rt] = (bf16x8){0,0,0,0,0,0,0,0};
          al[rt] = (bf16x8){0,0,0,0,0,0,0,0};
        }
      }
    } else {
#pragma unroll
      for (int rt = 0; rt < 2; ++rt) {
        float v[8] = {0,0,0,0,0,0,0,0};
        if (valid[rt]) {
          const float* base = in0f + (size_t)rown[rt] * HD + k0;
          float4 v0 = *(const float4*)base;
          float4 v1 = *(const float4*)(base + 4);
          v[0]=v0.x; v[1]=v0.y; v[2]=v0.z; v[3]=v0.w;
          v[4]=v1.x; v[5]=v1.y; v[6]=v1.z; v[7]=v1.w;
          if (SCALE0) {
#pragma unroll
            for (int e = 0; e < 8; ++e) v[e] *= scl[rt];
          }
        }
        unsigned h4[4], l4[4];
#pragma unroll
        for (int e = 0; e < 4; ++e) bsplit2(v[e*2], v[e*2+1], h4[e], l4[e]);
        ah[rt] = __builtin_bit_cast(bf16x8, *(uint4*)h4);
        al[rt] = __builtin_bit_cast(bf16x8, *(uint4*)l4);
      }
    }
#pragma unroll
    for (int ct = 0; ct < 8; ++ct) {
      const size_t boff = (size_t)(((ktg * 8 + ct) * 64) + lane) * 8;
      bf16x8 bh = *(const bf16x8*)&Wn[boff];
      bf16x8 bl = *(const bf16x8*)&Wlo[boff];
#pragma unroll
      for (int rt = 0; rt < 2; ++rt) {
        acc[rt][ct] = __builtin_amdgcn_mfma_f32_16x16x32_bf16(ah[rt], bh, acc[rt][ct], 0, 0, 0);
        acc[rt][ct] = __builtin_amdgcn_mfma_f32_16x16x32_bf16(al[rt], bh, acc[rt][ct], 0, 0, 0);
        acc[rt][ct] = __builtin_amdgcn_mfma_f32_16x16x32_bf16(ah[rt], bl, acc[rt][ct], 0, 0, 0);
      }
    }
  }

#pragma unroll
  for (int rt = 0; rt < 2; ++rt) {
    int rbase = m0 + w4 * 32 + rt * 16 + lk * 4;
    float m2[4];
#pragma unroll
    for (int reg = 0; reg < 4; ++reg) {
      int row = rbase + reg;
      m2[reg] = (BIAS2 && row < M && sc[row] > 0.f) ? 1.f : 0.f;
    }
#pragma unroll
    for (int ct = 0; ct < 8; ++ct) {
      int col = ct * 16 + lrow;
      float bv = bias ? bias[col] : 0.f;
      float b2v = BIAS2 ? bias2[col] : 0.f;
#pragma unroll
      for (int reg = 0; reg < 4; ++reg) {
        int row = rbase + reg;
        if (row < M) {
          float v = acc[rt][ct][reg] + bv + m2[reg] * b2v;
          if (RELU && v < 0.f) v = 0.f;
          if (OUTMODE == 1) {
            outh[(size_t)row * HD + col] = (unsigned short)rne16(v);
          } else {
            unsigned short hi, lo;
            bsplit(v, hi, lo);
            outh[(size_t)row * HD + col] = hi;
            outl[(size_t)row * HD + col] = lo;
          }
        }
      }
    }
  }
}

// ---- zero Pagg rows that receive atomics -----------------------------------
__global__ void bzero_k(const unsigned int* __restrict__ spk, float* __restrict__ Pagg,
                        int nwg) {
  int g = blockIdx.x * 256 + threadIdx.x;
  int idx = g >> 5, l32 = g & 31;
  if (idx >= nwg - 1) return;
  int dst = (int)(spk[(idx + 1) * 128] >> 16);
  *(float4*)&Pagg[(size_t)dst * HD + l32 * 4] = (float4){0.f, 0.f, 0.f, 0.f};
}

// ---- fused edge kernel -----------------------------------------------------
__global__ __launch_bounds__(256, 4) void edge_k(
    const unsigned int* __restrict__ spk, const float* __restrict__ pos,
    const unsigned short* __restrict__ hAb,
    const float* __restrict__ w31, const float* __restrict__ b31,
    const unsigned short* __restrict__ Wpk, const float* __restrict__ ub,
    float* __restrict__ Pagg, int E, int nwg)
{
  __shared__ __align__(16) unsigned short Tw[128 * 128];
  __shared__ int SS[128];
  __shared__ int SD[128];
  __shared__ int segstart[132];
  __shared__ int segdst[132];
  __shared__ int sScal[4];
  const int tid = threadIdx.x;
  const int lane = tid & 63, w4 = tid >> 6;

  int b = blockIdx.x;
  int q = nwg >> 3, r = nwg & 7;
  int xcd = b & 7, sub = b >> 3;
  int wg = (xcd < r ? xcd * (q + 1) : r * (q + 1) + (xcd - r) * q) + sub;
  const int e0 = wg * 128;

  {
    int el = tid & 127;
    int p = e0 + el;
    int s = 0, d = -1;
    float d0 = 0.f, d1 = 0.f, d2 = 0.f;
    if (p < E) {
      unsigned int pk = spk[p];
      s = (int)(pk & 0xffffu);
      d = (int)(pk >> 16);
      d0 = pos[(size_t)s*3+0] - pos[(size_t)d*3+0];
      d1 = pos[(size_t)s*3+1] - pos[(size_t)d*3+1];
      d2 = pos[(size_t)s*3+2] - pos[(size_t)d*3+2];
    }
    if (tid < 128) { SS[tid] = s; SD[tid] = d; }
    if (tid == 0) sScal[0] = (e0 > 0) ? (int)(spk[e0-1] >> 16) : -2;
    if (tid == 1) sScal[1] = (e0 + 128 < E) ? (int)(spk[e0+128] >> 16) : -2;
    int k0 = (tid >> 7) * 64;
    int swz = el & 7;
#pragma unroll
    for (int g = 0; g < 8; ++g) {
      int kb = (k0 >> 3) + g;
      float v[8];
#pragma unroll
      for (int j = 0; j < 8; ++j) {
        int k = k0 + g*8 + j;
        float t = fmaf(d0, w31[k], fmaf(d1, w31[128+k], fmaf(d2, w31[256+k], b31[k])));
        v[j] = t > 0.f ? t : 0.f;
      }
      uint4 w;
      w.x = pk2(v[0], v[1]); w.y = pk2(v[2], v[3]);
      w.z = pk2(v[4], v[5]); w.w = pk2(v[6], v[7]);
      *(uint4*)&Tw[el * 128 + ((kb ^ swz) << 3)] = w;
    }
  }
  __syncthreads();

  bool head = false;
  if (tid < 128) {
    int d = SD[tid];
    head = (tid == 0) ? true : (d != SD[tid - 1]);
  }
  unsigned long long bal = __ballot(head);
  int rank = __popcll(bal & ((1ull << lane) - 1));
  if (tid == 0) sScal[2] = 0;
  if (tid == 63) sScal[2] = rank + (head ? 1 : 0);

  const int ty = tid >> 4, tx = tid & 15;
  uint4 hv[8];
#pragma unroll
  for (int i = 0; i < 8; ++i) {
    int s = SS[ty*8 + i];
    hv[i] = *(const uint4*)&hAb[(size_t)s * HD + tx*8];
  }
  __syncthreads();
  if (tid < 128) {
    int rr = rank + ((tid >= 64) ? sScal[2] : 0);
    if (head) { segstart[rr] = tid; segdst[rr] = SD[tid]; }
  }
  if (tid == 64) sScal[3] = sScal[2] + __popcll(bal);

  const int lrow = lane & 15, lk = lane >> 4;
  f32x4 acc[2][8];
#pragma unroll
  for (int rt = 0; rt < 2; ++rt)
#pragma unroll
    for (int ct = 0; ct < 8; ++ct) acc[rt][ct] = (f32x4){0.f, 0.f, 0.f, 0.f};

#pragma unroll
  for (int kt = 0; kt < 4; ++kt) {
    bf16x8 a[2];
#pragma unroll
    for (int rt = 0; rt < 2; ++rt) {
      int e = w4*32 + rt*16 + lrow;
      int kb = kt*4 + lk;
      a[rt] = *(const bf16x8*)&Tw[e * 128 + ((kb ^ (e & 7)) << 3)];
    }
#pragma unroll
    for (int cg = 0; cg < 2; ++cg) {
      bf16x8 bq[4];
#pragma unroll
      for (int c4 = 0; c4 < 4; ++c4)
        bq[c4] = *(const bf16x8*)&Wpk[(size_t)(((kt*8 + cg*4 + c4) * 64) + lane) * 8];
#pragma unroll
      for (int rt = 0; rt < 2; ++rt)
#pragma unroll
        for (int c4 = 0; c4 < 4; ++c4)
          acc[rt][cg*4 + c4] = __builtin_amdgcn_mfma_f32_16x16x32_bf16(
              a[rt], bq[c4], acc[rt][cg*4 + c4], 0, 0, 0);
    }
  }
  __syncthreads();

#pragma unroll
  for (int rt = 0; rt < 2; ++rt) {
    int ebase = w4*32 + rt*16 + lk*4;
#pragma unroll
    for (int ct = 0; ct < 8; ++ct) {
      int c = ct*16 + lrow;
      Tw[(ebase+0)*128 + c] = (unsigned short)rne16(acc[rt][ct][0]);
      Tw[(ebase+1)*128 + c] = (unsigned short)rne16(acc[rt][ct][1]);
      Tw[(ebase+2)*128 + c] = (unsigned short)rne16(acc[rt][ct][2]);
      Tw[(ebase+3)*128 + c] = (unsigned short)rne16(acc[rt][ct][3]);
    }
  }
  __syncthreads();

  {
    float4 u0 = *(const float4*)&ub[tx*8];
    float4 u1 = *(const float4*)&ub[tx*8+4];
    float ubv[8] = {u0.x,u0.y,u0.z,u0.w,u1.x,u1.y,u1.z,u1.w};
#pragma unroll
    for (int i = 0; i < 8; ++i) {
      int row = ty*8 + i;
      uint4 uv = *(const uint4*)&Tw[row * 128 + tx*8];
      float uvv[8] = {blo(uv.x),bhi(uv.x),blo(uv.y),bhi(uv.y),
                      blo(uv.z),bhi(uv.z),blo(uv.w),bhi(uv.w)};
      float hvv[8] = {blo(hv[i].x),bhi(hv[i].x),blo(hv[i].y),bhi(hv[i].y),
                      blo(hv[i].z),bhi(hv[i].z),blo(hv[i].w),bhi(hv[i].w)};
      float p[8];
#pragma unroll
      for (int j = 0; j < 8; ++j) {
        float v = uvv[j] + hvv[j] + ubv[j];
        p[j] = v > 0.f ? v : 0.f;
      }
      uint4 w;
      w.x = pk2(p[0], p[1]); w.y = pk2(p[2], p[3]);
      w.z = pk2(p[4], p[5]); w.w = pk2(p[6], p[7]);
      *(uint4*)&Tw[row * 128 + tx*8] = w;
    }
  }
  __syncthreads();

  {
    const int nseg = sScal[3];
    const int dprev = sScal[0], dnext = sScal[1];
    for (int s = w4; s < nseg; s += 4) {
      int dst = segdst[s];
      if (dst < 0) continue;
      int r0 = segstart[s];
      int r1 = (s + 1 < nseg) ? segstart[s + 1] : 128;
      float sx = 0.f, sy = 0.f;
      for (int rr = r0; rr < r1; ++rr) {
        unsigned v = *(const unsigned*)&Tw[rr * 128 + lane * 2];
        sx += blo(v); sy += bhi(v);
      }
      float* pp = &Pagg[(size_t)dst * HD + lane * 2];
      if (dst == dprev || dst == dnext) {
        atomicAdd(pp, sx);
        atomicAdd(pp + 1, sy);
      } else {
        float2 st = {sx, sy};
        *(float2*)pp = st;
      }
    }
  }
}

// ---- readout phase 1: reads hi plane directly ------------------------------
__global__ __launch_bounds__(256, 4) void readout1_k(
    const unsigned short* __restrict__ hH, const float* __restrict__ l1w,
    const float* __restrict__ l1b, const float* __restrict__ l2w,
    const float* __restrict__ l2b, float* __restrict__ ybuf, int n)
{
  __shared__ __align__(16) unsigned short Bh[8192];
  const int tid = threadIdx.x;
  const int lane = tid & 63, w4 = tid >> 6;
  const int lrow = lane & 15, lk = lane >> 4;
  const int m0 = blockIdx.x * 128;

  for (int it = 0; it < 4; ++it) {
    int g = tid + it * 256;
    int kt = g >> 8, ct = (g >> 6) & 3, ln = g & 63;
    int row = kt * 32 + ((ln >> 4) << 3);
    int col = ct * 16 + (ln & 15);
    unsigned short h8[8];
#pragma unroll
    for (int e = 0; e < 8; ++e) h8[e] = (unsigned short)rne16(l1w[(size_t)(row + e) * 64 + col]);
    uint4 p = {(unsigned)h8[0] | ((unsigned)h8[1] << 16),
               (unsigned)h8[2] | ((unsigned)h8[3] << 16),
               (unsigned)h8[4] | ((unsigned)h8[5] << 16),
               (unsigned)h8[6] | ((unsigned)h8[7] << 16)};
    *(uint4*)&Bh[g * 8] = p;
  }
  __syncthreads();

  f32x4 acc[2][4];
#pragma unroll
  for (int rt = 0; rt < 2; ++rt)
#pragma unroll
    for (int ct = 0; ct < 4; ++ct) acc[rt][ct] = (f32x4){0.f, 0.f, 0.f, 0.f};

#pragma unroll
  for (int kt = 0; kt < 4; ++kt) {
    int k0 = kt * 32 + lk * 8;
    bf16x8 a[2];
#pragma unroll
    for (int rt = 0; rt < 2; ++rt) {
      int row = m0 + w4 * 32 + rt * 16 + lrow;
      if (row < n) a[rt] = *(const bf16x8*)&hH[(size_t)row * HD + k0];
      else a[rt] = (bf16x8){0,0,0,0,0,0,0,0};
    }
#pragma unroll
    for (int ct = 0; ct < 4; ++ct) {
      bf16x8 b = *(const bf16x8*)&Bh[(((kt * 4 + ct) * 64) + lane) * 8];
#pragma unroll
      for (int rt = 0; rt < 2; ++rt)
        acc[rt][ct] = __builtin_amdgcn_mfma_f32_16x16x32_bf16(a[rt], b, acc[rt][ct], 0, 0, 0);
    }
  }

  const float l2b0 = l2b[0];
#pragma unroll
  for (int rt = 0; rt < 2; ++rt) {
    float yp[4] = {0.f, 0.f, 0.f, 0.f};
#pragma unroll
    for (int ct = 0; ct < 4; ++ct) {
      int col = ct * 16 + lrow;
      float b1 = l1b[col], w2 = l2w[col];
#pragma unroll
      for (int reg = 0; reg < 4; ++reg) {
        float z = acc[rt][ct][reg] + b1;
        yp[reg] = fmaf(z > 0.f ? z : 0.f, w2, yp[reg]);
      }
    }
#pragma unroll
    for (int reg = 0; reg < 4; ++reg) {
#pragma unroll
      for (int off = 1; off < 16; off <<= 1) yp[reg] += __shfl_xor(yp[reg], off);
      int row = m0 + w4 * 32 + rt * 16 + lk * 4 + reg;
      if (lrow == 0 && row < n) ybuf[row] = yp[reg] + l2b0;
    }
  }
}

// ---- readout phase 2 -------------------------------------------------------
__global__ void readout2_k(const float* __restrict__ ybuf, const int* __restrict__ batch,
                           float* __restrict__ out, int n) {
  int t = blockIdx.x * 256 + threadIdx.x;
  int base = t * 8;
  if (base >= n) return;
  int bprev = batch[base];
  float s = ybuf[base];
  for (int i = 1; i < 8; ++i) {
    int idx = base + i;
    if (idx >= n) break;
    int bb = batch[idx];
    if (bb != bprev) { atomicAdd(&out[bprev], s); s = 0.f; bprev = bb; }
    s += ybuf[idx];
  }
  atomicAdd(&out[bprev], s);
}

extern "C" void kernel_launch(void* const* d_in, const int* in_sizes, int n_in,
                              void* d_out, int out_size, void* d_ws, size_t ws_size,
                              hipStream_t stream) {
  const float* x     = (const float*)d_in[0];
  const float* pos   = (const float*)d_in[1];
  const int*   ei    = (const int*)d_in[2];
  const int*   batch = (const int*)d_in[3];
  const float* nw1   = (const float*)d_in[4];
  const float* nb1   = (const float*)d_in[5];
  const float* nw2   = (const float*)d_in[6];
  const float* nb2   = (const float*)d_in[7];
  const float* m1w1  = (const float*)d_in[8];
  const float* m1b1  = (const float*)d_in[9];
  const float* m1w2  = (const float*)d_in[10];
  const float* m1b2  = (const float*)d_in[11];
  const float* m2w1  = (const float*)d_in[12];
  const float* m2b1  = (const float*)d_in[13];
  const float* m2w2  = (const float*)d_in[14];
  const float* m2b2  = (const float*)d_in[15];
  const float* m3w1  = (const float*)d_in[16];
  const float* m3b1  = (const float*)d_in[17];
  const float* m3w2  = (const float*)d_in[18];
  const float* m3b2  = (const float*)d_in[19];
  const float* l1w   = (const float*)d_in[20];
  const float* l1b   = (const float*)d_in[21];
  const float* l2w   = (const float*)d_in[22];
  const float* l2b   = (const float*)d_in[23];

  const int N = in_sizes[0];
  const int E = in_sizes[2] / 2;
  const int L = in_sizes[8] / (256 * 128);

  float* Pagg = (float*)d_ws;                                   // [N,128] f32
  unsigned int* spk = (unsigned int*)(Pagg + (size_t)N * HD);   // [E]
  int*   cnt  = (int*)(spk + E);                                // [N]
  float* invd = (float*)(cnt + N);                              // [N]
  float* Wf   = invd + N;                                       // [L,128,128]
  float* ub   = Wf + (size_t)L * 128 * 128;                     // [L,128]
  float* Wm   = ub + (size_t)L * 128;                           // [L,128,128]
  float* bfold= Wm + (size_t)L * 128 * 128;                     // [L,128]
  unsigned short* hAb = (unsigned short*)(bfold + (size_t)L * 128);  // [N,128]
  unsigned short* Wpk = hAb + (size_t)N * HD;                   // [L,16384]
  float* ybuf = (float*)(Wpk + (size_t)L * 16384);              // [N]
  int*   bsum = (int*)(ybuf + N);                               // [128]
  unsigned short* WnBase = (unsigned short*)(bsum + 128);
  unsigned short* WnInit = WnBase;
  unsigned short* WnW2a[3], *WnCat[3], *WnW2[3];
  unsigned short* planes;
  {
    unsigned short* p = WnBase + 32768;
    for (int l = 0; l < 3; ++l) {
      WnW2a[l] = p; p += 32768;
      WnCat[l] = p; p += 65536;
      WnW2[l]  = p; p += 32768;
    }
    planes = p;
  }
  unsigned short* hH = planes;                 // [N,128]
  unsigned short* hL = hH + (size_t)N * HD;
  unsigned short* tH = hL + (size_t)N * HD;
  unsigned short* tL = tH + (size_t)N * HD;

  hipMemsetAsync(cnt, 0, (size_t)N * sizeof(int), stream);
  hipMemsetAsync(d_out, 0, (size_t)out_size * sizeof(float), stream);

  count_k<<<(E + 255) / 256, 256, 0, stream>>>(ei, cnt, E);
  const int nsb = (N + 511) / 512;
  scanA_k<<<nsb, 512, 0, stream>>>(cnt, bsum, N);
  scanB_k<<<1, 128, 0, stream>>>(bsum, nsb);
  scanC_k<<<nsb, 512, 0, stream>>>(cnt, invd, bsum, N);
  scatter_k<<<(E + 255) / 256, 256, 0, stream>>>(ei, cnt, spk, E);
  fold_all_k<<<dim3(128, L, 2), 128, 0, stream>>>(m3w2, m2w1, m3b2, m2b1,
                                                  m2w2, m1w1, m2b2, Wf, ub, Wm, bfold);
  pack_k<<<dim3(64, L), 256, 0, stream>>>(Wf, Wpk);

  {
    PArgs pa;
    pa.d[0] = {nw2, nullptr, WnInit, 4};
    for (int l = 0; l < L; ++l) {
      pa.d[1 + l * 3] = {m2w1 + (size_t)l * 256 * 128, nullptr, WnW2a[l], 4};
      pa.d[2 + l * 3] = {Wm + (size_t)l * 128 * 128,
                         m1w1 + (size_t)l * 256 * 128 + 128 * 128, WnCat[l], 8};
      pa.d[3 + l * 3] = {m1w2 + (size_t)l * 128 * 128, nullptr, WnW2[l], 4};
    }
    packw_k<<<dim3(128, 1 + L * 3), 256, 0, stream>>>(pa);
  }

  const int gblk = (N + 127) / 128;
  // h = relu(x*nw1+nb1) @ nw2 + nb2  -> split planes
  gemm_mfma<4, false, false, false, false, 2, true><<<gblk, 256, 0, stream>>>(
      x, nullptr, nullptr, nullptr, nullptr, nullptr, WnInit,
      nb2, nullptr, nw1, nb1, hH, hL, N);

  const int nwg = (E + 127) / 128;
  const int nbz = ((nwg - 1) * 32 + 255) / 256;
  for (int l = 0; l < L; ++l) {
    // hAb = bf16(h @ W2a)
    gemm_mfma<4, false, false, false, true, 1, false><<<gblk, 256, 0, stream>>>(
        nullptr, hH, hL, nullptr, nullptr, nullptr, WnW2a[l],
        nullptr, nullptr, nullptr, nullptr, hAb, nullptr, N);
    bzero_k<<<nbz, 256, 0, stream>>>(spk, Pagg, nwg);
    edge_k<<<nwg, 256, 0, stream>>>(
        spk, pos, hAb,
        m3w1 + (size_t)l * 3 * 128, m3b1 + (size_t)l * 128,
        Wpk + (size_t)l * 16384, ub + (size_t)l * 128,
        Pagg, E, nwg);
    // tmp = relu((Pagg*invd)@Wm + [deg>0]*bf + h@W1b + m1b1) -> split planes
    gemm_mfma<8, true, true, true, false, 2, false><<<gblk, 256, 0, stream>>>(
        Pagg, nullptr, nullptr, hH, hL, invd, WnCat[l],
        m1b1 + (size_t)l * 128, bfold + (size_t)l * 128, nullptr, nullptr, tH, tL, N);
    // h = relu(tmp @ m1w2 + m1b2) -> split planes
    gemm_mfma<4, true, false, false, true, 2, false><<<gblk, 256, 0, stream>>>(
        nullptr, tH, tL, nullptr, nullptr, nullptr, WnW2[l],
        m1b2 + (size_t)l * 128, nullptr, nullptr, nullptr, hH, hL, N);
  }

  readout1_k<<<gblk, 256, 0, stream>>>(hH, l1w, l1b, l2w, l2b, ybuf, N);
  readout2_k<<<(N + 2047) / 2048, 256, 0, stream>>>(ybuf, batch, (float*)d_out, N);
}

// Round 9
// 726.023 us; speedup vs baseline: 1.0134x; 1.0134x over previous
//
#include <hip/hip_runtime.h>

#define HD 128

typedef __attribute__((ext_vector_type(8))) short bf16x8;
typedef __attribute__((ext_vector_type(4))) float f32x4;

// ---- bf16 helpers ----------------------------------------------------------
__device__ __forceinline__ unsigned rne16(float x) {
  unsigned u = __builtin_bit_cast(unsigned, x);
  return (u + 0x7fffu + ((u >> 16) & 1u)) >> 16;
}
__device__ __forceinline__ unsigned pk2(float a, float b) {  // HW v_cvt_pk_bf16_f32
  unsigned r;
  asm("v_cvt_pk_bf16_f32 %0, %1, %2" : "=v"(r) : "v"(a), "v"(b));
  return r;
}
__device__ __forceinline__ float blo(unsigned u) { return __builtin_bit_cast(float, u << 16); }
__device__ __forceinline__ float bhi(unsigned u) { return __builtin_bit_cast(float, u & 0xffff0000u); }
__device__ __forceinline__ float bval(unsigned h16) { return __builtin_bit_cast(float, h16 << 16); }

__device__ __forceinline__ void bsplit(float v, unsigned short& hi, unsigned short& lo) {
  unsigned h = rne16(v);
  hi = (unsigned short)h;
  lo = (unsigned short)rne16(v - bval(h));
}
__device__ __forceinline__ void bsplit2(float v0, float v1, unsigned& hi, unsigned& lo) {
  hi = pk2(v0, v1);
  lo = pk2(v0 - bval(hi & 0xffffu), v1 - bval(hi >> 16));
}

// ---- degree count ----------------------------------------------------------
__global__ void count_k(const int* __restrict__ ei, int* __restrict__ cnt, int E) {
  int e = blockIdx.x * 256 + threadIdx.x;
  if (e < E) atomicAdd(&cnt[ei[E + e]], 1);
}

// ---- 3-phase multi-block exclusive scan ------------------------------------
__global__ __launch_bounds__(512) void scanA_k(const int* __restrict__ cnt,
                                               int* __restrict__ bsum, int n) {
  __shared__ int ws[8];
  const int tid = threadIdx.x, lane = tid & 63, wid = tid >> 6;
  int i = blockIdx.x * 512 + tid;
  int v = (i < n) ? cnt[i] : 0;
#pragma unroll
  for (int off = 32; off > 0; off >>= 1) v += __shfl_xor(v, off);
  if (lane == 0) ws[wid] = v;
  __syncthreads();
  if (tid == 0) {
    int s = 0;
#pragma unroll
    for (int w = 0; w < 8; ++w) s += ws[w];
    bsum[blockIdx.x] = s;
  }
}

__global__ __launch_bounds__(128) void scanB_k(int* __restrict__ bsum, int nb) {
  __shared__ int w2[2];
  const int tid = threadIdx.x, lane = tid & 63, wid = tid >> 6;
  int v = (tid < nb) ? bsum[tid] : 0;
  int s = v;
#pragma unroll
  for (int off = 1; off < 64; off <<= 1) {
    int u = __shfl_up(s, off);
    if (lane >= off) s += u;
  }
  if (lane == 63) w2[wid] = s;
  __syncthreads();
  int add = (wid == 1) ? w2[0] : 0;
  if (tid < nb) bsum[tid] = s - v + add;
}

__global__ __launch_bounds__(512) void scanC_k(int* __restrict__ cnt, float* __restrict__ invd,
                                               const int* __restrict__ bsum, int n) {
  __shared__ int ws[8];
  const int tid = threadIdx.x, lane = tid & 63, wid = tid >> 6;
  int i = blockIdx.x * 512 + tid;
  int v = (i < n) ? cnt[i] : 0;
  int s = v;
#pragma unroll
  for (int off = 1; off < 64; off <<= 1) {
    int u = __shfl_up(s, off);
    if (lane >= off) s += u;
  }
  if (lane == 63) ws[wid] = s;
  __syncthreads();
  int wadd = 0;
  for (int w = 0; w < wid; ++w) wadd += ws[w];
  if (i < n) {
    cnt[i] = s - v + wadd + bsum[blockIdx.x];
    invd[i] = v > 0 ? 1.f / (float)v : 0.f;
  }
}

// ---- scatter into dst-sorted order: spk[p] = src | (dst<<16) ---------------
__global__ void scatter_k(const int* __restrict__ ei, int* __restrict__ cur,
                          unsigned int* __restrict__ spk, int E) {
  int e = blockIdx.x * 256 + threadIdx.x;
  if (e >= E) return;
  int s = ei[e], d = ei[E + e];
  int p = atomicAdd(&cur[d], 1);
  spk[p] = (unsigned int)s | ((unsigned int)d << 16);
}

// ---- weight folding --------------------------------------------------------
__global__ void fold_all_k(const float* __restrict__ m3w2, const float* __restrict__ m2w1,
                           const float* __restrict__ m3b2, const float* __restrict__ m2b1,
                           const float* __restrict__ m2w2, const float* __restrict__ m1w1,
                           const float* __restrict__ m2b2,
                           float* __restrict__ Wf, float* __restrict__ ub,
                           float* __restrict__ Wm, float* __restrict__ bf) {
  const int k = blockIdx.x, l = blockIdx.y, mode = blockIdx.z, c = threadIdx.x;
  const float *A, *B, *bA, *badd;
  float *O, *ob;
  if (mode == 0) {
    A = m3w2 + (size_t)l * 128 * 128;
    B = m2w1 + (size_t)l * 256 * 128 + 128 * 128;
    bA = m3b2 + (size_t)l * 128; badd = m2b1 + (size_t)l * 128;
    O = Wf + (size_t)l * 128 * 128; ob = ub + (size_t)l * 128;
  } else {
    A = m2w2 + (size_t)l * 128 * 128;
    B = m1w1 + (size_t)l * 256 * 128;
    bA = m2b2 + (size_t)l * 128; badd = nullptr;
    O = Wm + (size_t)l * 128 * 128; ob = bf + (size_t)l * 128;
  }
  float s = 0.f;
  for (int r = 0; r < 128; ++r) s = fmaf(A[k * 128 + r], B[r * 128 + c], s);
  O[k * 128 + c] = s;
  if (k == 0) {
    float t = badd ? badd[c] : 0.f;
    for (int r = 0; r < 128; ++r) t = fmaf(bA[r], B[r * 128 + c], t);
    ob[c] = t;
  }
}

// ---- pack Wf into bf16 MFMA B-fragment order (edge kernel, hi only) --------
__global__ void pack_k(const float* __restrict__ Wf, unsigned short* __restrict__ Wpk) {
  int l = blockIdx.y;
  int flat = blockIdx.x * 256 + threadIdx.x;
  int e = flat & 7, l6 = (flat >> 3) & 63, ct = (flat >> 9) & 7, kt = flat >> 12;
  int row = kt * 32 + ((l6 >> 4) << 3) + e;
  int col = ct * 16 + (l6 & 15);
  Wpk[(size_t)l * 16384 + flat] =
      (unsigned short)rne16(Wf[(size_t)l * 16384 + row * 128 + col]);
}

// ---- pack node-GEMM weights into hi/lo B-fragment buffers ------------------
struct PDesc { const float* w0; const float* w1; unsigned short* out; int kt; };
struct PArgs { PDesc d[10]; };

__global__ void packw_k(PArgs pa) {
  PDesc de = pa.d[blockIdx.y];
  int flat = blockIdx.x * 256 + threadIdx.x;
  int tot = de.kt * 4096;
  if (flat >= tot) return;
  int e = flat & 7, ln = (flat >> 3) & 63, ct = (flat >> 9) & 7, kt = flat >> 12;
  int row = kt * 32 + ((ln >> 4) << 3) + e;
  int col = ct * 16 + (ln & 15);
  float v = (row < 128) ? de.w0[(size_t)row * 128 + col]
                        : de.w1[(size_t)(row - 128) * 128 + col];
  unsigned short hi, lo;
  bsplit(v, hi, lo);
  de.out[flat] = hi;
  de.out[tot + flat] = lo;
}

// ---- node GEMM via MFMA, 64 rows/block, optional fused 2nd GEMM ------------
// A: AINIT -> relu(x*aw+ab); SPLIT0 -> in0h/in0l; else f32 in0 (opt SCALE0).
// KT==8 upper K-half reads in1h/in1l. OUTMODE: 1 = hi only, 2 = hi/lo planes.
// FUSE: stage bf16(out) in LDS, second MFMA pass outA = bf16out @ Wa.
template<int KT, bool RELU, bool SCALE0, bool BIAS2, bool SPLIT0, int OUTMODE,
         bool AINIT, bool FUSE>
__global__ __launch_bounds__(256) void gemm_mfma(
    const float* __restrict__ in0f,
    const unsigned short* __restrict__ in0h, const unsigned short* __restrict__ in0l,
    const unsigned short* __restrict__ in1h, const unsigned short* __restrict__ in1l,
    const float* __restrict__ sc, const unsigned short* __restrict__ Wn,
    const float* __restrict__ bias, const float* __restrict__ bias2,
    const float* __restrict__ aw, const float* __restrict__ ab,
    unsigned short* __restrict__ outh, unsigned short* __restrict__ outl,
    const unsigned short* __restrict__ Wa, unsigned short* __restrict__ outA, int M)
{
  __shared__ __align__(16) unsigned short hT[FUSE ? 64 * 128 : 16];
  const int tid = threadIdx.x;
  const int lane = tid & 63, w4 = tid >> 6;
  const int lrow = lane & 15, lk = lane >> 4;
  const int m0 = blockIdx.x * 64;
  const unsigned short* __restrict__ Wlo = Wn + KT * 4096;

  const int rown = m0 + w4 * 16 + lrow;
  const bool valid = rown < M;
  const float scl = (SCALE0 && valid) ? sc[rown] : 1.f;
  const float xv = (AINIT && valid) ? in0f[rown] : 0.f;

  f32x4 acc[8];
#pragma unroll
  for (int ct = 0; ct < 8; ++ct) acc[ct] = (f32x4){0.f, 0.f, 0.f, 0.f};

#pragma unroll
  for (int ktg = 0; ktg < KT; ++ktg) {
    const int k0 = ktg * 32 + lk * 8;
    bf16x8 ah, al;
    if (AINIT) {
      float4 a0 = *(const float4*)&aw[k0];
      float4 a1 = *(const float4*)&aw[k0 + 4];
      float4 b0 = *(const float4*)&ab[k0];
      float4 b1 = *(const float4*)&ab[k0 + 4];
      float awv[8] = {a0.x,a0.y,a0.z,a0.w,a1.x,a1.y,a1.z,a1.w};
      float abv[8] = {b0.x,b0.y,b0.z,b0.w,b1.x,b1.y,b1.z,b1.w};
      unsigned h4[4], l4[4];
#pragma unroll
      for (int e = 0; e < 4; ++e) {
        float v0 = fmaf(xv, awv[e*2], abv[e*2]);
        float v1 = fmaf(xv, awv[e*2+1], abv[e*2+1]);
        v0 = v0 > 0.f ? v0 : 0.f;
        v1 = v1 > 0.f ? v1 : 0.f;
        bsplit2(v0, v1, h4[e], l4[e]);
      }
      ah = __builtin_bit_cast(bf16x8, *(uint4*)h4);
      al = __builtin_bit_cast(bf16x8, *(uint4*)l4);
    } else if (KT == 8 && k0 >= 128) {
      if (valid) {
        ah = *(const bf16x8*)&in1h[(size_t)rown * HD + (k0 - 128)];
        al = *(const bf16x8*)&in1l[(size_t)rown * HD + (k0 - 128)];
      } else {
        ah = (bf16x8){0,0,0,0,0,0,0,0};
        al = (bf16x8){0,0,0,0,0,0,0,0};
      }
    } else if (SPLIT0) {
      if (valid) {
        ah = *(const bf16x8*)&in0h[(size_t)rown * HD + k0];
        al = *(const bf16x8*)&in0l[(size_t)rown * HD + k0];
      } else {
        ah = (bf16x8){0,0,0,0,0,0,0,0};
        al = (bf16x8){0,0,0,0,0,0,0,0};
      }
    } else {
      float v[8] = {0,0,0,0,0,0,0,0};
      if (valid) {
        const float* base = in0f + (size_t)rown * HD + k0;
        float4 v0 = *(const float4*)base;
        float4 v1 = *(const float4*)(base + 4);
        v[0]=v0.x; v[1]=v0.y; v[2]=v0.z; v[3]=v0.w;
        v[4]=v1.x; v[5]=v1.y; v[6]=v1.z; v[7]=v1.w;
        if (SCALE0) {
#pragma unroll
          for (int e = 0; e < 8; ++e) v[e] *= scl;
        }
      }
      unsigned h4[4], l4[4];
#pragma unroll
      for (int e = 0; e < 4; ++e) bsplit2(v[e*2], v[e*2+1], h4[e], l4[e]);
      ah = __builtin_bit_cast(bf16x8, *(uint4*)h4);
      al = __builtin_bit_cast(bf16x8, *(uint4*)l4);
    }
#pragma unroll
    for (int ct = 0; ct < 8; ++ct) {
      const size_t boff = (size_t)(((ktg * 8 + ct) * 64) + lane) * 8;
      bf16x8 bh = *(const bf16x8*)&Wn[boff];
      bf16x8 bl = *(const bf16x8*)&Wlo[boff];
      acc[ct] = __builtin_amdgcn_mfma_f32_16x16x32_bf16(ah, bh, acc[ct], 0, 0, 0);
      acc[ct] = __builtin_amdgcn_mfma_f32_16x16x32_bf16(al, bh, acc[ct], 0, 0, 0);
      acc[ct] = __builtin_amdgcn_mfma_f32_16x16x32_bf16(ah, bl, acc[ct], 0, 0, 0);
    }
  }

  // epilogue (+ LDS stage for fused pass)
  {
    const int rbase = m0 + w4 * 16 + lk * 4;
    float m2[4];
#pragma unroll
    for (int reg = 0; reg < 4; ++reg) {
      int row = rbase + reg;
      m2[reg] = (BIAS2 && row < M && sc[row] > 0.f) ? 1.f : 0.f;
    }
#pragma unroll
    for (int ct = 0; ct < 8; ++ct) {
      int col = ct * 16 + lrow;
      float bv = bias ? bias[col] : 0.f;
      float b2v = BIAS2 ? bias2[col] : 0.f;
#pragma unroll
      for (int reg = 0; reg < 4; ++reg) {
        int row = rbase + reg;
        if (row < M) {
          float v = acc[ct][reg] + bv + m2[reg] * b2v;
          if (RELU && v < 0.f) v = 0.f;
          unsigned short hi, lo;
          bsplit(v, hi, lo);
          outh[(size_t)row * HD + col] = hi;
          if (OUTMODE == 2) outl[(size_t)row * HD + col] = lo;
          if (FUSE) {
            int lr = w4 * 16 + lk * 4 + reg;
            hT[lr * 128 + ((((col >> 3) ^ (lr & 7)) << 3) | (col & 7))] = hi;
          }
        }
      }
    }
  }

  if constexpr (FUSE) {
    __syncthreads();
    const unsigned short* __restrict__ Walo = Wa + 16384;
    f32x4 ac2[8];
#pragma unroll
    for (int ct = 0; ct < 8; ++ct) ac2[ct] = (f32x4){0.f, 0.f, 0.f, 0.f};
#pragma unroll
    for (int ktg = 0; ktg < 4; ++ktg) {
      const int lr = w4 * 16 + lrow;
      const int kb = ktg * 4 + lk;
      bf16x8 a = *(const bf16x8*)&hT[lr * 128 + ((kb ^ (lr & 7)) << 3)];
#pragma unroll
      for (int ct = 0; ct < 8; ++ct) {
        const size_t boff = (size_t)(((ktg * 8 + ct) * 64) + lane) * 8;
        bf16x8 bh = *(const bf16x8*)&Wa[boff];
        bf16x8 bl = *(const bf16x8*)&Walo[boff];
        ac2[ct] = __builtin_amdgcn_mfma_f32_16x16x32_bf16(a, bh, ac2[ct], 0, 0, 0);
        ac2[ct] = __builtin_amdgcn_mfma_f32_16x16x32_bf16(a, bl, ac2[ct], 0, 0, 0);
      }
    }
    const int rbase = m0 + w4 * 16 + lk * 4;
#pragma unroll
    for (int ct = 0; ct < 8; ++ct) {
      int col = ct * 16 + lrow;
#pragma unroll
      for (int reg = 0; reg < 4; ++reg) {
        int row = rbase + reg;
        if (row < M) outA[(size_t)row * HD + col] = (unsigned short)rne16(ac2[ct][reg]);
      }
    }
  }
}

// ---- zero Pagg rows that receive atomics -----------------------------------
__global__ void bzero_k(const unsigned int* __restrict__ spk, float* __restrict__ Pagg,
                        int nwg) {
  int g = blockIdx.x * 256 + threadIdx.x;
  int idx = g >> 5, l32 = g & 31;
  if (idx >= nwg - 1) return;
  int dst = (int)(spk[(idx + 1) * 128] >> 16);
  *(float4*)&Pagg[(size_t)dst * HD + l32 * 4] = (float4){0.f, 0.f, 0.f, 0.f};
}

// ---- fused edge kernel ------------------------------------------------------
__global__ __launch_bounds__(256, 4) void edge_k(
    const unsigned int* __restrict__ spk, const float* __restrict__ pos,
    const unsigned short* __restrict__ hAb,
    const float* __restrict__ w31, const float* __restrict__ b31,
    const unsigned short* __restrict__ Wpk, const float* __restrict__ ub,
    float* __restrict__ Pagg, int E, int nwg)
{
  __shared__ __align__(16) unsigned short Tw[128 * 128];
  __shared__ int SD[128];
  __shared__ int segstart[132];
  __shared__ int segdst[132];
  __shared__ int sScal[4];
  const int tid = threadIdx.x;
  const int lane = tid & 63, w4 = tid >> 6;
  const int ty = tid >> 4, tx = tid & 15;

  int b = blockIdx.x;
  int q = nwg >> 3, r = nwg & 7;
  int xcd = b & 7, sub = b >> 3;
  int wg = (xcd < r ? xcd * (q + 1) : r * (q + 1) + (xcd - r) * q) + sub;
  const int e0 = wg * 128;

  // early hA gather: issue at kernel start; latency hides under stage-1 + MFMA
  uint4 hv[8];
#pragma unroll
  for (int i = 0; i < 8; ++i) {
    int p = e0 + ty * 8 + i;
    unsigned pk = (p < E) ? spk[p] : 0u;
    hv[i] = *(const uint4*)&hAb[(size_t)(pk & 0xffffu) * HD + tx * 8];
  }

  // stage 1: t = relu(dist @ w31 + b31) -> bf16 LDS (A-frag layout, swizzled)
  {
    int el = tid & 127;
    int p = e0 + el;
    int d = -1;
    float d0 = 0.f, d1 = 0.f, d2 = 0.f;
    if (p < E) {
      unsigned int pk = spk[p];
      int s = (int)(pk & 0xffffu);
      d = (int)(pk >> 16);
      d0 = pos[(size_t)s*3+0] - pos[(size_t)d*3+0];
      d1 = pos[(size_t)s*3+1] - pos[(size_t)d*3+1];
      d2 = pos[(size_t)s*3+2] - pos[(size_t)d*3+2];
    }
    if (tid < 128) SD[tid] = d;
    if (tid == 0) sScal[0] = (e0 > 0) ? (int)(spk[e0-1] >> 16) : -2;
    if (tid == 1) sScal[1] = (e0 + 128 < E) ? (int)(spk[e0+128] >> 16) : -2;
    int k0 = (tid >> 7) * 64;
    int swz = el & 7;
#pragma unroll
    for (int g = 0; g < 8; ++g) {
      int kb = (k0 >> 3) + g;
      float v[8];
#pragma unroll
      for (int j = 0; j < 8; ++j) {
        int k = k0 + g*8 + j;
        float t = fmaf(d0, w31[k], fmaf(d1, w31[128+k], fmaf(d2, w31[256+k], b31[k])));
        v[j] = t > 0.f ? t : 0.f;
      }
      uint4 w;
      w.x = pk2(v[0], v[1]); w.y = pk2(v[2], v[3]);
      w.z = pk2(v[4], v[5]); w.w = pk2(v[6], v[7]);
      *(uint4*)&Tw[el * 128 + ((kb ^ swz) << 3)] = w;
    }
  }
  __syncthreads();

  // segment heads (2-wave ballot)
  bool head = false;
  if (tid < 128) {
    int d = SD[tid];
    head = (tid == 0) ? true : (d != SD[tid - 1]);
  }
  unsigned long long bal = __ballot(head);
  int rank = __popcll(bal & ((1ull << lane) - 1));
  if (tid == 0) sScal[2] = 0;
  if (tid == 63) sScal[2] = rank + (head ? 1 : 0);
  __syncthreads();
  if (tid < 128) {
    int rr = rank + ((tid >= 64) ? sScal[2] : 0);
    if (head) { segstart[rr] = tid; segdst[rr] = SD[tid]; }
  }
  if (tid == 64) sScal[3] = sScal[2] + __popcll(bal);

  // u = t @ Wf via MFMA
  const int lrow = lane & 15, lk = lane >> 4;
  f32x4 acc[2][8];
#pragma unroll
  for (int rt = 0; rt < 2; ++rt)
#pragma unroll
    for (int ct = 0; ct < 8; ++ct) acc[rt][ct] = (f32x4){0.f, 0.f, 0.f, 0.f};

#pragma unroll
  for (int kt = 0; kt < 4; ++kt) {
    bf16x8 a[2];
#pragma unroll
    for (int rt = 0; rt < 2; ++rt) {
      int e = w4*32 + rt*16 + lrow;
      int kb = kt*4 + lk;
      a[rt] = *(const bf16x8*)&Tw[e * 128 + ((kb ^ (e & 7)) << 3)];
    }
#pragma unroll
    for (int cg = 0; cg < 2; ++cg) {
      bf16x8 bq[4];
#pragma unroll
      for (int c4 = 0; c4 < 4; ++c4)
        bq[c4] = *(const bf16x8*)&Wpk[(size_t)(((kt*8 + cg*4 + c4) * 64) + lane) * 8];
#pragma unroll
      for (int rt = 0; rt < 2; ++rt)
#pragma unroll
        for (int c4 = 0; c4 < 4; ++c4)
          acc[rt][cg*4 + c4] = __builtin_amdgcn_mfma_f32_16x16x32_bf16(
              a[rt], bq[c4], acc[rt][cg*4 + c4], 0, 0, 0);
    }
  }
  __syncthreads();

  // u (bf16) -> Tw as [e][c]
#pragma unroll
  for (int rt = 0; rt < 2; ++rt) {
    int ebase = w4*32 + rt*16 + lk*4;
#pragma unroll
    for (int ct = 0; ct < 8; ++ct) {
      int c = ct*16 + lrow;
      Tw[(ebase+0)*128 + c] = (unsigned short)rne16(acc[rt][ct][0]);
      Tw[(ebase+1)*128 + c] = (unsigned short)rne16(acc[rt][ct][1]);
      Tw[(ebase+2)*128 + c] = (unsigned short)rne16(acc[rt][ct][2]);
      Tw[(ebase+3)*128 + c] = (unsigned short)rne16(acc[rt][ct][3]);
    }
  }
  __syncthreads();

  // P = relu(u + hA[src] + ub) in place (bf16)
  {
    float4 u0 = *(const float4*)&ub[tx*8];
    float4 u1 = *(const float4*)&ub[tx*8+4];
    float ubv[8] = {u0.x,u0.y,u0.z,u0.w,u1.x,u1.y,u1.z,u1.w};
#pragma unroll
    for (int i = 0; i < 8; ++i) {
      int row = ty*8 + i;
      uint4 uv = *(const uint4*)&Tw[row * 128 + tx*8];
      float uvv[8] = {blo(uv.x),bhi(uv.x),blo(uv.y),bhi(uv.y),
                      blo(uv.z),bhi(uv.z),blo(uv.w),bhi(uv.w)};
      float hvv[8] = {blo(hv[i].x),bhi(hv[i].x),blo(hv[i].y),bhi(hv[i].y),
                      blo(hv[i].z),bhi(hv[i].z),blo(hv[i].w),bhi(hv[i].w)};
      float p[8];
#pragma unroll
      for (int j = 0; j < 8; ++j) {
        float v = uvv[j] + hvv[j] + ubv[j];
        p[j] = v > 0.f ? v : 0.f;
      }
      uint4 w;
      w.x = pk2(p[0], p[1]); w.y = pk2(p[2], p[3]);
      w.z = pk2(p[4], p[5]); w.w = pk2(p[6], p[7]);
      *(uint4*)&Tw[row * 128 + tx*8] = w;
    }
  }
  __syncthreads();

  // segment reduce: plain store unless segment crosses a block boundary
  {
    const int nseg = sScal[3];
    const int dprev = sScal[0], dnext = sScal[1];
    for (int s = w4; s < nseg; s += 4) {
      int dst = segdst[s];
      if (dst < 0) continue;
      int r0 = segstart[s];
      int r1 = (s + 1 < nseg) ? segstart[s + 1] : 128;
      float sx = 0.f, sy = 0.f;
      for (int rr = r0; rr < r1; ++rr) {
        unsigned v = *(const unsigned*)&Tw[rr * 128 + lane * 2];
        sx += blo(v); sy += bhi(v);
      }
      float* pp = &Pagg[(size_t)dst * HD + lane * 2];
      if (dst == dprev || dst == dnext) {
        atomicAdd(pp, sx);
        atomicAdd(pp + 1, sy);
      } else {
        float2 st = {sx, sy};
        *(float2*)pp = st;
      }
    }
  }
}

// ---- readout phase 1 --------------------------------------------------------
__global__ __launch_bounds__(256, 4) void readout1_k(
    const unsigned short* __restrict__ hH, const float* __restrict__ l1w,
    const float* __restrict__ l1b, const float* __restrict__ l2w,
    const float* __restrict__ l2b, float* __restrict__ ybuf, int n)
{
  __shared__ __align__(16) unsigned short Bh[8192];
  const int tid = threadIdx.x;
  const int lane = tid & 63, w4 = tid >> 6;
  const int lrow = lane & 15, lk = lane >> 4;
  const int m0 = blockIdx.x * 128;

  for (int it = 0; it < 4; ++it) {
    int g = tid + it * 256;
    int kt = g >> 8, ct = (g >> 6) & 3, ln = g & 63;
    int row = kt * 32 + ((ln >> 4) << 3);
    int col = ct * 16 + (ln & 15);
    unsigned short h8[8];
#pragma unroll
    for (int e = 0; e < 8; ++e) h8[e] = (unsigned short)rne16(l1w[(size_t)(row + e) * 64 + col]);
    uint4 p = {(unsigned)h8[0] | ((unsigned)h8[1] << 16),
               (unsigned)h8[2] | ((unsigned)h8[3] << 16),
               (unsigned)h8[4] | ((unsigned)h8[5] << 16),
               (unsigned)h8[6] | ((unsigned)h8[7] << 16)};
    *(uint4*)&Bh[g * 8] = p;
  }
  __syncthreads();

  f32x4 acc[2][4];
#pragma unroll
  for (int rt = 0; rt < 2; ++rt)
#pragma unroll
    for (int ct = 0; ct < 4; ++ct) acc[rt][ct] = (f32x4){0.f, 0.f, 0.f, 0.f};

#pragma unroll
  for (int kt = 0; kt < 4; ++kt) {
    int k0 = kt * 32 + lk * 8;
    bf16x8 a[2];
#pragma unroll
    for (int rt = 0; rt < 2; ++rt) {
      int row = m0 + w4 * 32 + rt * 16 + lrow;
      if (row < n) a[rt] = *(const bf16x8*)&hH[(size_t)row * HD + k0];
      else a[rt] = (bf16x8){0,0,0,0,0,0,0,0};
    }
#pragma unroll
    for (int ct = 0; ct < 4; ++ct) {
      bf16x8 b = *(const bf16x8*)&Bh[(((kt * 4 + ct) * 64) + lane) * 8];
#pragma unroll
      for (int rt = 0; rt < 2; ++rt)
        acc[rt][ct] = __builtin_amdgcn_mfma_f32_16x16x32_bf16(a[rt], b, acc[rt][ct], 0, 0, 0);
    }
  }

  const float l2b0 = l2b[0];
#pragma unroll
  for (int rt = 0; rt < 2; ++rt) {
    float yp[4] = {0.f, 0.f, 0.f, 0.f};
#pragma unroll
    for (int ct = 0; ct < 4; ++ct) {
      int col = ct * 16 + lrow;
      float b1 = l1b[col], w2 = l2w[col];
#pragma unroll
      for (int reg = 0; reg < 4; ++reg) {
        float z = acc[rt][ct][reg] + b1;
        yp[reg] = fmaf(z > 0.f ? z : 0.f, w2, yp[reg]);
      }
    }
#pragma unroll
    for (int reg = 0; reg < 4; ++reg) {
#pragma unroll
      for (int off = 1; off < 16; off <<= 1) yp[reg] += __shfl_xor(yp[reg], off);
      int row = m0 + w4 * 32 + rt * 16 + lk * 4 + reg;
      if (lrow == 0 && row < n) ybuf[row] = yp[reg] + l2b0;
    }
  }
}

// ---- readout phase 2 --------------------------------------------------------
__global__ void readout2_k(const float* __restrict__ ybuf, const int* __restrict__ batch,
                           float* __restrict__ out, int n) {
  int t = blockIdx.x * 256 + threadIdx.x;
  int base = t * 8;
  if (base >= n) return;
  int bprev = batch[base];
  float s = ybuf[base];
  for (int i = 1; i < 8; ++i) {
    int idx = base + i;
    if (idx >= n) break;
    int bb = batch[idx];
    if (bb != bprev) { atomicAdd(&out[bprev], s); s = 0.f; bprev = bb; }
    s += ybuf[idx];
  }
  atomicAdd(&out[bprev], s);
}

extern "C" void kernel_launch(void* const* d_in, const int* in_sizes, int n_in,
                              void* d_out, int out_size, void* d_ws, size_t ws_size,
                              hipStream_t stream) {
  const float* x     = (const float*)d_in[0];
  const float* pos   = (const float*)d_in[1];
  const int*   ei    = (const int*)d_in[2];
  const int*   batch = (const int*)d_in[3];
  const float* nw1   = (const float*)d_in[4];
  const float* nb1   = (const float*)d_in[5];
  const float* nw2   = (const float*)d_in[6];
  const float* nb2   = (const float*)d_in[7];
  const float* m1w1  = (const float*)d_in[8];
  const float* m1b1  = (const float*)d_in[9];
  const float* m1w2  = (const float*)d_in[10];
  const float* m1b2  = (const float*)d_in[11];
  const float* m2w1  = (const float*)d_in[12];
  const float* m2b1  = (const float*)d_in[13];
  const float* m2w2  = (const float*)d_in[14];
  const float* m2b2  = (const float*)d_in[15];
  const float* m3w1  = (const float*)d_in[16];
  const float* m3b1  = (const float*)d_in[17];
  const float* m3w2  = (const float*)d_in[18];
  const float* m3b2  = (const float*)d_in[19];
  const float* l1w   = (const float*)d_in[20];
  const float* l1b   = (const float*)d_in[21];
  const float* l2w   = (const float*)d_in[22];
  const float* l2b   = (const float*)d_in[23];

  const int N = in_sizes[0];
  const int E = in_sizes[2] / 2;
  const int L = in_sizes[8] / (256 * 128);

  float* Pagg = (float*)d_ws;                                   // [N,128] f32
  unsigned int* spk = (unsigned int*)(Pagg + (size_t)N * HD);   // [E]
  int*   cnt  = (int*)(spk + E);                                // [N]
  float* invd = (float*)(cnt + N);                              // [N]
  float* Wf   = invd + N;                                       // [L,128,128]
  float* ub   = Wf + (size_t)L * 128 * 128;                     // [L,128]
  float* Wm   = ub + (size_t)L * 128;                           // [L,128,128]
  float* bfold= Wm + (size_t)L * 128 * 128;                     // [L,128]
  unsigned short* hAb = (unsigned short*)(bfold + (size_t)L * 128);  // [N,128]
  unsigned short* Wpk = hAb + (size_t)N * HD;                   // [L,16384]
  float* ybuf = (float*)(Wpk + (size_t)L * 16384);              // [N]
  int*   bsum = (int*)(ybuf + N);                               // [128]
  unsigned short* WnBase = (unsigned short*)(bsum + 128);
  unsigned short* WnInit = WnBase;
  unsigned short* WnW2a[3], *WnCat[3], *WnW2[3];
  unsigned short* planes;
  {
    unsigned short* p = WnBase + 32768;
    for (int l = 0; l < 3; ++l) {
      WnW2a[l] = p; p += 32768;
      WnCat[l] = p; p += 65536;
      WnW2[l]  = p; p += 32768;
    }
    planes = p;
  }
  unsigned short* hH = planes;                 // [N,128]
  unsigned short* hL = hH + (size_t)N * HD;
  unsigned short* tH = hL + (size_t)N * HD;
  unsigned short* tL = tH + (size_t)N * HD;

  hipMemsetAsync(cnt, 0, (size_t)N * sizeof(int), stream);
  hipMemsetAsync(d_out, 0, (size_t)out_size * sizeof(float), stream);

  count_k<<<(E + 255) / 256, 256, 0, stream>>>(ei, cnt, E);
  const int nsb = (N + 511) / 512;
  scanA_k<<<nsb, 512, 0, stream>>>(cnt, bsum, N);
  scanB_k<<<1, 128, 0, stream>>>(bsum, nsb);
  scanC_k<<<nsb, 512, 0, stream>>>(cnt, invd, bsum, N);
  scatter_k<<<(E + 255) / 256, 256, 0, stream>>>(ei, cnt, spk, E);
  fold_all_k<<<dim3(128, L, 2), 128, 0, stream>>>(m3w2, m2w1, m3b2, m2b1,
                                                  m2w2, m1w1, m2b2, Wf, ub, Wm, bfold);
  pack_k<<<dim3(64, L), 256, 0, stream>>>(Wf, Wpk);

  {
    PArgs pa;
    pa.d[0] = {nw2, nullptr, WnInit, 4};
    for (int l = 0; l < L; ++l) {
      pa.d[1 + l * 3] = {m2w1 + (size_t)l * 256 * 128, nullptr, WnW2a[l], 4};
      pa.d[2 + l * 3] = {Wm + (size_t)l * 128 * 128,
                         m1w1 + (size_t)l * 256 * 128 + 128 * 128, WnCat[l], 8};
      pa.d[3 + l * 3] = {m1w2 + (size_t)l * 128 * 128, nullptr, WnW2[l], 4};
    }
    packw_k<<<dim3(128, 1 + L * 3), 256, 0, stream>>>(pa);
  }

  const int gblk = (N + 63) / 64;
  // h0 = relu(x*nw1+nb1)@nw2+nb2 -> planes ; fused: hAb = bf16(h0) @ W2a[0]
  gemm_mfma<4, false, false, false, false, 2, true, true><<<gblk, 256, 0, stream>>>(
      x, nullptr, nullptr, nullptr, nullptr, nullptr, WnInit,
      nb2, nullptr, nw1, nb1, hH, hL, WnW2a[0], hAb, N);

  const int nwg = (E + 127) / 128;
  const int nbz = ((nwg - 1) * 32 + 255) / 256;
  for (int l = 0; l < L; ++l) {
    bzero_k<<<nbz, 256, 0, stream>>>(spk, Pagg, nwg);
    edge_k<<<nwg, 256, 0, stream>>>(
        spk, pos, hAb,
        m3w1 + (size_t)l * 3 * 128, m3b1 + (size_t)l * 128,
        Wpk + (size_t)l * 16384, ub + (size_t)l * 128,
        Pagg, E, nwg);
    // tmp = relu((Pagg*invd)@Wm + [deg>0]*bf + h@W1b + m1b1) -> planes
    gemm_mfma<8, true, true, true, false, 2, false, false><<<gblk, 256, 0, stream>>>(
        Pagg, nullptr, nullptr, hH, hL, invd, WnCat[l],
        m1b1 + (size_t)l * 128, bfold + (size_t)l * 128, nullptr, nullptr,
        tH, tL, nullptr, nullptr, N);
    // h = relu(tmp @ m1w2 + m1b2) -> planes ; fused hAb for next layer
    if (l + 1 < L) {
      gemm_mfma<4, true, false, false, true, 2, false, true><<<gblk, 256, 0, stream>>>(
          nullptr, tH, tL, nullptr, nullptr, nullptr, WnW2[l],
          m1b2 + (size_t)l * 128, nullptr, nullptr, nullptr,
          hH, hL, WnW2a[l + 1], hAb, N);
    } else {
      gemm_mfma<4, true, false, false, true, 2, false, false><<<gblk, 256, 0, stream>>>(
          nullptr, tH, tL, nullptr, nullptr, nullptr, WnW2[l],
          m1b2 + (size_t)l * 128, nullptr, nullptr, nullptr,
          hH, hL, nullptr, nullptr, N);
    }
  }

  readout1_k<<<(N + 127) / 128, 256, 0, stream>>>(hH, l1w, l1b, l2w, l2b, ybuf, N);
  readout2_k<<<(N + 2047) / 2048, 256, 0, stream>>>(ybuf, batch, (float*)d_out, N);
}

// Round 10
// 710.261 us; speedup vs baseline: 1.0359x; 1.0222x over previous
//
#include <hip/hip_runtime.h>

#define HD 128

typedef __attribute__((ext_vector_type(8))) short bf16x8;
typedef __attribute__((ext_vector_type(4))) float f32x4;

// ---- bf16 helpers ----------------------------------------------------------
__device__ __forceinline__ unsigned rne16(float x) {
  unsigned u = __builtin_bit_cast(unsigned, x);
  return (u + 0x7fffu + ((u >> 16) & 1u)) >> 16;
}
__device__ __forceinline__ unsigned pk2(float a, float b) {  // HW v_cvt_pk_bf16_f32
  unsigned r;
  asm("v_cvt_pk_bf16_f32 %0, %1, %2" : "=v"(r) : "v"(a), "v"(b));
  return r;
}
__device__ __forceinline__ float blo(unsigned u) { return __builtin_bit_cast(float, u << 16); }
__device__ __forceinline__ float bhi(unsigned u) { return __builtin_bit_cast(float, u & 0xffff0000u); }
__device__ __forceinline__ float bval(unsigned h16) { return __builtin_bit_cast(float, h16 << 16); }

__device__ __forceinline__ void bsplit(float v, unsigned short& hi, unsigned short& lo) {
  unsigned h = rne16(v);
  hi = (unsigned short)h;
  lo = (unsigned short)rne16(v - bval(h));
}
__device__ __forceinline__ void bsplit2(float v0, float v1, unsigned& hi, unsigned& lo) {
  hi = pk2(v0, v1);
  lo = pk2(v0 - bval(hi & 0xffffu), v1 - bval(hi >> 16));
}
__device__ __forceinline__ int swzc(int col, int lr) {
  return (((col >> 3) ^ (lr & 7)) << 3) | (col & 7);
}

// ---- degree count ----------------------------------------------------------
__global__ void count_k(const int* __restrict__ ei, int* __restrict__ cnt, int E) {
  int e = blockIdx.x * 256 + threadIdx.x;
  if (e < E) atomicAdd(&cnt[ei[E + e]], 1);
}

// ---- 3-phase multi-block exclusive scan ------------------------------------
__global__ __launch_bounds__(512) void scanA_k(const int* __restrict__ cnt,
                                               int* __restrict__ bsum, int n) {
  __shared__ int ws[8];
  const int tid = threadIdx.x, lane = tid & 63, wid = tid >> 6;
  int i = blockIdx.x * 512 + tid;
  int v = (i < n) ? cnt[i] : 0;
#pragma unroll
  for (int off = 32; off > 0; off >>= 1) v += __shfl_xor(v, off);
  if (lane == 0) ws[wid] = v;
  __syncthreads();
  if (tid == 0) {
    int s = 0;
#pragma unroll
    for (int w = 0; w < 8; ++w) s += ws[w];
    bsum[blockIdx.x] = s;
  }
}

__global__ __launch_bounds__(128) void scanB_k(int* __restrict__ bsum, int nb) {
  __shared__ int w2[2];
  const int tid = threadIdx.x, lane = tid & 63, wid = tid >> 6;
  int v = (tid < nb) ? bsum[tid] : 0;
  int s = v;
#pragma unroll
  for (int off = 1; off < 64; off <<= 1) {
    int u = __shfl_up(s, off);
    if (lane >= off) s += u;
  }
  if (lane == 63) w2[wid] = s;
  __syncthreads();
  int add = (wid == 1) ? w2[0] : 0;
  if (tid < nb) bsum[tid] = s - v + add;
}

__global__ __launch_bounds__(512) void scanC_k(int* __restrict__ cnt, float* __restrict__ invd,
                                               const int* __restrict__ bsum, int n) {
  __shared__ int ws[8];
  const int tid = threadIdx.x, lane = tid & 63, wid = tid >> 6;
  int i = blockIdx.x * 512 + tid;
  int v = (i < n) ? cnt[i] : 0;
  int s = v;
#pragma unroll
  for (int off = 1; off < 64; off <<= 1) {
    int u = __shfl_up(s, off);
    if (lane >= off) s += u;
  }
  if (lane == 63) ws[wid] = s;
  __syncthreads();
  int wadd = 0;
  for (int w = 0; w < wid; ++w) wadd += ws[w];
  if (i < n) {
    cnt[i] = s - v + wadd + bsum[blockIdx.x];
    invd[i] = v > 0 ? 1.f / (float)v : 0.f;
  }
}

// ---- scatter into dst-sorted order -----------------------------------------
__global__ void scatter_k(const int* __restrict__ ei, int* __restrict__ cur,
                          unsigned int* __restrict__ spk, int E) {
  int e = blockIdx.x * 256 + threadIdx.x;
  if (e >= E) return;
  int s = ei[e], d = ei[E + e];
  int p = atomicAdd(&cur[d], 1);
  spk[p] = (unsigned int)s | ((unsigned int)d << 16);
}

// ---- weight folding --------------------------------------------------------
__global__ void fold_all_k(const float* __restrict__ m3w2, const float* __restrict__ m2w1,
                           const float* __restrict__ m3b2, const float* __restrict__ m2b1,
                           const float* __restrict__ m2w2, const float* __restrict__ m1w1,
                           const float* __restrict__ m2b2,
                           float* __restrict__ Wf, float* __restrict__ ub,
                           float* __restrict__ Wm, float* __restrict__ bf) {
  const int k = blockIdx.x, l = blockIdx.y, mode = blockIdx.z, c = threadIdx.x;
  const float *A, *B, *bA, *badd;
  float *O, *ob;
  if (mode == 0) {
    A = m3w2 + (size_t)l * 128 * 128;
    B = m2w1 + (size_t)l * 256 * 128 + 128 * 128;
    bA = m3b2 + (size_t)l * 128; badd = m2b1 + (size_t)l * 128;
    O = Wf + (size_t)l * 128 * 128; ob = ub + (size_t)l * 128;
  } else {
    A = m2w2 + (size_t)l * 128 * 128;
    B = m1w1 + (size_t)l * 256 * 128;
    bA = m2b2 + (size_t)l * 128; badd = nullptr;
    O = Wm + (size_t)l * 128 * 128; ob = bf + (size_t)l * 128;
  }
  float s = 0.f;
  for (int r = 0; r < 128; ++r) s = fmaf(A[k * 128 + r], B[r * 128 + c], s);
  O[k * 128 + c] = s;
  if (k == 0) {
    float t = badd ? badd[c] : 0.f;
    for (int r = 0; r < 128; ++r) t = fmaf(bA[r], B[r * 128 + c], t);
    ob[c] = t;
  }
}

// ---- pack Wf into bf16 B-fragment order (edge kernel, hi only) -------------
__global__ void pack_k(const float* __restrict__ Wf, unsigned short* __restrict__ Wpk) {
  int l = blockIdx.y;
  int flat = blockIdx.x * 256 + threadIdx.x;
  int e = flat & 7, l6 = (flat >> 3) & 63, ct = (flat >> 9) & 7, kt = flat >> 12;
  int row = kt * 32 + ((l6 >> 4) << 3) + e;
  int col = ct * 16 + (l6 & 15);
  Wpk[(size_t)l * 16384 + flat] =
      (unsigned short)rne16(Wf[(size_t)l * 16384 + row * 128 + col]);
}

// ---- pack node-GEMM weights into hi/lo B-fragment buffers ------------------
struct PDesc { const float* w0; const float* w1; unsigned short* out; int kt; };
struct PArgs { PDesc d[10]; };

__global__ void packw_k(PArgs pa) {
  PDesc de = pa.d[blockIdx.y];
  int flat = blockIdx.x * 256 + threadIdx.x;
  int tot = de.kt * 4096;
  if (flat >= tot) return;
  int e = flat & 7, ln = (flat >> 3) & 63, ct = (flat >> 9) & 7, kt = flat >> 12;
  int row = kt * 32 + ((ln >> 4) << 3) + e;
  int col = ct * 16 + (ln & 15);
  float v = (row < 128) ? de.w0[(size_t)row * 128 + col]
                        : de.w1[(size_t)(row - 128) * 128 + col];
  unsigned short hi, lo;
  bsplit(v, hi, lo);
  de.out[flat] = hi;
  de.out[tot + flat] = lo;
}

// ---- init GEMM: h = relu(x*aw+ab) @ Wn + bias -> planes ; fused hAb --------
__global__ __launch_bounds__(256) void init_k(
    const float* __restrict__ x, const unsigned short* __restrict__ Wn,
    const float* __restrict__ bias, const float* __restrict__ aw,
    const float* __restrict__ ab,
    unsigned short* __restrict__ outh, unsigned short* __restrict__ outl,
    const unsigned short* __restrict__ Wa, unsigned short* __restrict__ outA, int M)
{
  __shared__ __align__(16) unsigned short hT[64 * 128];
  const int tid = threadIdx.x;
  const int lane = tid & 63, w4 = tid >> 6;
  const int lrow = lane & 15, lk = lane >> 4;
  const int m0 = blockIdx.x * 64;
  const unsigned short* __restrict__ Wlo = Wn + 16384;

  const int rown = m0 + w4 * 16 + lrow;
  const bool valid = rown < M;
  const float xv = valid ? x[rown] : 0.f;

  f32x4 acc[8];
#pragma unroll
  for (int ct = 0; ct < 8; ++ct) acc[ct] = (f32x4){0.f, 0.f, 0.f, 0.f};

#pragma unroll
  for (int ktg = 0; ktg < 4; ++ktg) {
    const int k0 = ktg * 32 + lk * 8;
    float4 a0 = *(const float4*)&aw[k0];
    float4 a1 = *(const float4*)&aw[k0 + 4];
    float4 b0 = *(const float4*)&ab[k0];
    float4 b1 = *(const float4*)&ab[k0 + 4];
    float awv[8] = {a0.x,a0.y,a0.z,a0.w,a1.x,a1.y,a1.z,a1.w};
    float abv[8] = {b0.x,b0.y,b0.z,b0.w,b1.x,b1.y,b1.z,b1.w};
    unsigned h4[4], l4[4];
#pragma unroll
    for (int e = 0; e < 4; ++e) {
      float v0 = fmaf(xv, awv[e*2], abv[e*2]);
      float v1 = fmaf(xv, awv[e*2+1], abv[e*2+1]);
      v0 = v0 > 0.f ? v0 : 0.f;
      v1 = v1 > 0.f ? v1 : 0.f;
      bsplit2(v0, v1, h4[e], l4[e]);
    }
    bf16x8 ah = __builtin_bit_cast(bf16x8, *(uint4*)h4);
    bf16x8 al = __builtin_bit_cast(bf16x8, *(uint4*)l4);
#pragma unroll
    for (int ct = 0; ct < 8; ++ct) {
      const size_t boff = (size_t)(((ktg * 8 + ct) * 64) + lane) * 8;
      bf16x8 bh = *(const bf16x8*)&Wn[boff];
      bf16x8 bl = *(const bf16x8*)&Wlo[boff];
      acc[ct] = __builtin_amdgcn_mfma_f32_16x16x32_bf16(ah, bh, acc[ct], 0, 0, 0);
      acc[ct] = __builtin_amdgcn_mfma_f32_16x16x32_bf16(al, bh, acc[ct], 0, 0, 0);
      acc[ct] = __builtin_amdgcn_mfma_f32_16x16x32_bf16(ah, bl, acc[ct], 0, 0, 0);
    }
  }

  const int rbl = w4 * 16 + lk * 4;
#pragma unroll
  for (int ct = 0; ct < 8; ++ct) {
    int col = ct * 16 + lrow;
    float bv = bias[col];
#pragma unroll
    for (int reg = 0; reg < 4; ++reg) {
      int row = m0 + rbl + reg;
      if (row < M) {
        float v = acc[ct][reg] + bv;
        unsigned short hi, lo;
        bsplit(v, hi, lo);
        outh[(size_t)row * HD + col] = hi;
        outl[(size_t)row * HD + col] = lo;
        hT[(rbl + reg) * 128 + swzc(col, rbl + reg)] = hi;
      }
    }
  }

  // fused hAb = h_hi @ Wa  (wave-local rows, no barrier)
  const unsigned short* __restrict__ Walo = Wa + 16384;
  f32x4 ac2[8];
#pragma unroll
  for (int ct = 0; ct < 8; ++ct) ac2[ct] = (f32x4){0.f, 0.f, 0.f, 0.f};
#pragma unroll
  for (int ktg = 0; ktg < 4; ++ktg) {
    const int lr = w4 * 16 + lrow;
    const int kb = ktg * 4 + lk;
    bf16x8 a = *(const bf16x8*)&hT[lr * 128 + ((kb ^ (lr & 7)) << 3)];
#pragma unroll
    for (int ct = 0; ct < 8; ++ct) {
      const size_t boff = (size_t)(((ktg * 8 + ct) * 64) + lane) * 8;
      bf16x8 bh = *(const bf16x8*)&Wa[boff];
      bf16x8 bl = *(const bf16x8*)&Walo[boff];
      ac2[ct] = __builtin_amdgcn_mfma_f32_16x16x32_bf16(a, bh, ac2[ct], 0, 0, 0);
      ac2[ct] = __builtin_amdgcn_mfma_f32_16x16x32_bf16(a, bl, ac2[ct], 0, 0, 0);
    }
  }
#pragma unroll
  for (int ct = 0; ct < 8; ++ct) {
    int col = ct * 16 + lrow;
#pragma unroll
    for (int reg = 0; reg < 4; ++reg) {
      int row = m0 + rbl + reg;
      if (row < M) outA[(size_t)row * HD + col] = (unsigned short)rne16(ac2[ct][reg]);
    }
  }
}

// ---- fused layer kernel: cat-GEMM -> w2-GEMM -> (hAb GEMM) -----------------
// tmp = relu([Pagg*invd | h]@Wcat + b1 + [deg>0]*bf)   (LDS hi/lo, wave-local)
// h'  = relu(tmp @ W2 + b2) -> hHo/hLo planes
// hA  = h'_hi @ Wa -> outA   (skipped when LAST)
template<bool LAST>
__global__ __launch_bounds__(256) void layer_k(
    const float* __restrict__ Pagg,
    const unsigned short* __restrict__ hH, const unsigned short* __restrict__ hL,
    const float* __restrict__ invd,
    const unsigned short* __restrict__ Wcat, const float* __restrict__ b1,
    const float* __restrict__ bf,
    const unsigned short* __restrict__ W2, const float* __restrict__ b2,
    const unsigned short* __restrict__ Wa,
    unsigned short* __restrict__ hHo, unsigned short* __restrict__ hLo,
    unsigned short* __restrict__ outA, int M)
{
  __shared__ __align__(16) unsigned short tmpH[64 * 128];
  __shared__ __align__(16) unsigned short tmpL[64 * 128];
  const int tid = threadIdx.x;
  const int lane = tid & 63, w4 = tid >> 6;
  const int lrow = lane & 15, lk = lane >> 4;
  const int m0 = blockIdx.x * 64;

  const int rown = m0 + w4 * 16 + lrow;
  const bool valid = rown < M;
  const float scl = valid ? invd[rown] : 0.f;

  // ---- pass 1: cat GEMM (K=256) ----
  const unsigned short* __restrict__ Wclo = Wcat + 32768;
  f32x4 acc[8];
#pragma unroll
  for (int ct = 0; ct < 8; ++ct) acc[ct] = (f32x4){0.f, 0.f, 0.f, 0.f};

#pragma unroll
  for (int ktg = 0; ktg < 8; ++ktg) {
    const int k0 = ktg * 32 + lk * 8;
    bf16x8 ah, al;
    if (k0 >= 128) {
      if (valid) {
        ah = *(const bf16x8*)&hH[(size_t)rown * HD + (k0 - 128)];
        al = *(const bf16x8*)&hL[(size_t)rown * HD + (k0 - 128)];
      } else {
        ah = (bf16x8){0,0,0,0,0,0,0,0};
        al = (bf16x8){0,0,0,0,0,0,0,0};
      }
    } else {
      float v[8] = {0,0,0,0,0,0,0,0};
      if (valid) {
        const float* base = Pagg + (size_t)rown * HD + k0;
        float4 v0 = *(const float4*)base;
        float4 v1 = *(const float4*)(base + 4);
        v[0]=v0.x*scl; v[1]=v0.y*scl; v[2]=v0.z*scl; v[3]=v0.w*scl;
        v[4]=v1.x*scl; v[5]=v1.y*scl; v[6]=v1.z*scl; v[7]=v1.w*scl;
      }
      unsigned h4[4], l4[4];
#pragma unroll
      for (int e = 0; e < 4; ++e) bsplit2(v[e*2], v[e*2+1], h4[e], l4[e]);
      ah = __builtin_bit_cast(bf16x8, *(uint4*)h4);
      al = __builtin_bit_cast(bf16x8, *(uint4*)l4);
    }
#pragma unroll
    for (int ct = 0; ct < 8; ++ct) {
      const size_t boff = (size_t)(((ktg * 8 + ct) * 64) + lane) * 8;
      bf16x8 bh = *(const bf16x8*)&Wcat[boff];
      bf16x8 bl = *(const bf16x8*)&Wclo[boff];
      acc[ct] = __builtin_amdgcn_mfma_f32_16x16x32_bf16(ah, bh, acc[ct], 0, 0, 0);
      acc[ct] = __builtin_amdgcn_mfma_f32_16x16x32_bf16(al, bh, acc[ct], 0, 0, 0);
      acc[ct] = __builtin_amdgcn_mfma_f32_16x16x32_bf16(ah, bl, acc[ct], 0, 0, 0);
    }
  }

  // epilogue 1: stage tmp hi/lo into LDS (wave-local rows -> no barrier)
  const int rbl = w4 * 16 + lk * 4;
  float m2[4];
#pragma unroll
  for (int reg = 0; reg < 4; ++reg) {
    int row = m0 + rbl + reg;
    m2[reg] = (row < M && invd[row] > 0.f) ? 1.f : 0.f;
  }
#pragma unroll
  for (int ct = 0; ct < 8; ++ct) {
    int col = ct * 16 + lrow;
    float bv = b1[col], bfv = bf[col];
#pragma unroll
    for (int reg = 0; reg < 4; ++reg) {
      int lr = rbl + reg;
      float v = acc[ct][reg] + bv + m2[reg] * bfv;
      if (v < 0.f) v = 0.f;
      unsigned short hi, lo;
      bsplit(v, hi, lo);
      int sp = lr * 128 + swzc(col, lr);
      tmpH[sp] = hi;
      tmpL[sp] = lo;
    }
  }

  // ---- pass 2: h' = relu(tmp @ W2 + b2) ----
  const unsigned short* __restrict__ W2lo = W2 + 16384;
  f32x4 ac2[8];
#pragma unroll
  for (int ct = 0; ct < 8; ++ct) ac2[ct] = (f32x4){0.f, 0.f, 0.f, 0.f};
#pragma unroll
  for (int ktg = 0; ktg < 4; ++ktg) {
    const int lr = w4 * 16 + lrow;
    const int off = lr * 128 + (((ktg * 4 + lk) ^ (lr & 7)) << 3);
    bf16x8 aH = *(const bf16x8*)&tmpH[off];
    bf16x8 aL = *(const bf16x8*)&tmpL[off];
#pragma unroll
    for (int ct = 0; ct < 8; ++ct) {
      const size_t boff = (size_t)(((ktg * 8 + ct) * 64) + lane) * 8;
      bf16x8 bh = *(const bf16x8*)&W2[boff];
      bf16x8 bl = *(const bf16x8*)&W2lo[boff];
      ac2[ct] = __builtin_amdgcn_mfma_f32_16x16x32_bf16(aH, bh, ac2[ct], 0, 0, 0);
      ac2[ct] = __builtin_amdgcn_mfma_f32_16x16x32_bf16(aL, bh, ac2[ct], 0, 0, 0);
      ac2[ct] = __builtin_amdgcn_mfma_f32_16x16x32_bf16(aH, bl, ac2[ct], 0, 0, 0);
    }
  }
  // epilogue 2: write h planes; stage hi into tmpL (own rows; reads done)
#pragma unroll
  for (int ct = 0; ct < 8; ++ct) {
    int col = ct * 16 + lrow;
    float bv = b2[col];
#pragma unroll
    for (int reg = 0; reg < 4; ++reg) {
      int row = m0 + rbl + reg;
      if (row < M) {
        float v = ac2[ct][reg] + bv;
        if (v < 0.f) v = 0.f;
        unsigned short hi, lo;
        bsplit(v, hi, lo);
        hHo[(size_t)row * HD + col] = hi;
        hLo[(size_t)row * HD + col] = lo;
        if (!LAST) {
          int lr = rbl + reg;
          tmpL[lr * 128 + swzc(col, lr)] = hi;
        }
      }
    }
  }

  // ---- pass 3: hA = h'_hi @ Wa ----
  if constexpr (!LAST) {
    const unsigned short* __restrict__ Walo = Wa + 16384;
    f32x4 ac3[8];
#pragma unroll
    for (int ct = 0; ct < 8; ++ct) ac3[ct] = (f32x4){0.f, 0.f, 0.f, 0.f};
#pragma unroll
    for (int ktg = 0; ktg < 4; ++ktg) {
      const int lr = w4 * 16 + lrow;
      bf16x8 a = *(const bf16x8*)&tmpL[lr * 128 + (((ktg * 4 + lk) ^ (lr & 7)) << 3)];
#pragma unroll
      for (int ct = 0; ct < 8; ++ct) {
        const size_t boff = (size_t)(((ktg * 8 + ct) * 64) + lane) * 8;
        bf16x8 bh = *(const bf16x8*)&Wa[boff];
        bf16x8 bl = *(const bf16x8*)&Walo[boff];
        ac3[ct] = __builtin_amdgcn_mfma_f32_16x16x32_bf16(a, bh, ac3[ct], 0, 0, 0);
        ac3[ct] = __builtin_amdgcn_mfma_f32_16x16x32_bf16(a, bl, ac3[ct], 0, 0, 0);
      }
    }
#pragma unroll
    for (int ct = 0; ct < 8; ++ct) {
      int col = ct * 16 + lrow;
#pragma unroll
      for (int reg = 0; reg < 4; ++reg) {
        int row = m0 + rbl + reg;
        if (row < M) outA[(size_t)row * HD + col] = (unsigned short)rne16(ac3[ct][reg]);
      }
    }
  }
}

// ---- zero Pagg rows that receive atomics -----------------------------------
__global__ void bzero_k(const unsigned int* __restrict__ spk, float* __restrict__ Pagg,
                        int nwg) {
  int g = blockIdx.x * 256 + threadIdx.x;
  int idx = g >> 5, l32 = g & 31;
  if (idx >= nwg - 1) return;
  int dst = (int)(spk[(idx + 1) * 128] >> 16);
  *(float4*)&Pagg[(size_t)dst * HD + l32 * 4] = (float4){0.f, 0.f, 0.f, 0.f};
}

// ---- fused edge kernel (r8 structure: gather after stage-1) ----------------
__global__ __launch_bounds__(256, 4) void edge_k(
    const unsigned int* __restrict__ spk, const float* __restrict__ pos,
    const unsigned short* __restrict__ hAb,
    const float* __restrict__ w31, const float* __restrict__ b31,
    const unsigned short* __restrict__ Wpk, const float* __restrict__ ub,
    float* __restrict__ Pagg, int E, int nwg)
{
  __shared__ __align__(16) unsigned short Tw[128 * 128];
  __shared__ int SS[128];
  __shared__ int SD[128];
  __shared__ int segstart[132];
  __shared__ int segdst[132];
  __shared__ int sScal[4];
  const int tid = threadIdx.x;
  const int lane = tid & 63, w4 = tid >> 6;

  int b = blockIdx.x;
  int q = nwg >> 3, r = nwg & 7;
  int xcd = b & 7, sub = b >> 3;
  int wg = (xcd < r ? xcd * (q + 1) : r * (q + 1) + (xcd - r) * q) + sub;
  const int e0 = wg * 128;

  {
    int el = tid & 127;
    int p = e0 + el;
    int s = 0, d = -1;
    float d0 = 0.f, d1 = 0.f, d2 = 0.f;
    if (p < E) {
      unsigned int pk = spk[p];
      s = (int)(pk & 0xffffu);
      d = (int)(pk >> 16);
      d0 = pos[(size_t)s*3+0] - pos[(size_t)d*3+0];
      d1 = pos[(size_t)s*3+1] - pos[(size_t)d*3+1];
      d2 = pos[(size_t)s*3+2] - pos[(size_t)d*3+2];
    }
    if (tid < 128) { SS[tid] = s; SD[tid] = d; }
    if (tid == 0) sScal[0] = (e0 > 0) ? (int)(spk[e0-1] >> 16) : -2;
    if (tid == 1) sScal[1] = (e0 + 128 < E) ? (int)(spk[e0+128] >> 16) : -2;
    int k0 = (tid >> 7) * 64;
    int swz = el & 7;
#pragma unroll
    for (int g = 0; g < 8; ++g) {
      int kb = (k0 >> 3) + g;
      float v[8];
#pragma unroll
      for (int j = 0; j < 8; ++j) {
        int k = k0 + g*8 + j;
        float t = fmaf(d0, w31[k], fmaf(d1, w31[128+k], fmaf(d2, w31[256+k], b31[k])));
        v[j] = t > 0.f ? t : 0.f;
      }
      uint4 w;
      w.x = pk2(v[0], v[1]); w.y = pk2(v[2], v[3]);
      w.z = pk2(v[4], v[5]); w.w = pk2(v[6], v[7]);
      *(uint4*)&Tw[el * 128 + ((kb ^ swz) << 3)] = w;
    }
  }
  __syncthreads();

  bool head = false;
  if (tid < 128) {
    int d = SD[tid];
    head = (tid == 0) ? true : (d != SD[tid - 1]);
  }
  unsigned long long bal = __ballot(head);
  int rank = __popcll(bal & ((1ull << lane) - 1));
  if (tid == 0) sScal[2] = 0;
  if (tid == 63) sScal[2] = rank + (head ? 1 : 0);

  const int ty = tid >> 4, tx = tid & 15;
  uint4 hv[8];
#pragma unroll
  for (int i = 0; i < 8; ++i) {
    int s = SS[ty*8 + i];
    hv[i] = *(const uint4*)&hAb[(size_t)s * HD + tx*8];
  }
  __syncthreads();
  if (tid < 128) {
    int rr = rank + ((tid >= 64) ? sScal[2] : 0);
    if (head) { segstart[rr] = tid; segdst[rr] = SD[tid]; }
  }
  if (tid == 64) sScal[3] = sScal[2] + __popcll(bal);

  const int lrow = lane & 15, lk = lane >> 4;
  f32x4 acc[2][8];
#pragma unroll
  for (int rt = 0; rt < 2; ++rt)
#pragma unroll
    for (int ct = 0; ct < 8; ++ct) acc[rt][ct] = (f32x4){0.f, 0.f, 0.f, 0.f};

#pragma unroll
  for (int kt = 0; kt < 4; ++kt) {
    bf16x8 a[2];
#pragma unroll
    for (int rt = 0; rt < 2; ++rt) {
      int e = w4*32 + rt*16 + lrow;
      int kb = kt*4 + lk;
      a[rt] = *(const bf16x8*)&Tw[e * 128 + ((kb ^ (e & 7)) << 3)];
    }
#pragma unroll
    for (int cg = 0; cg < 2; ++cg) {
      bf16x8 bq[4];
#pragma unroll
      for (int c4 = 0; c4 < 4; ++c4)
        bq[c4] = *(const bf16x8*)&Wpk[(size_t)(((kt*8 + cg*4 + c4) * 64) + lane) * 8];
#pragma unroll
      for (int rt = 0; rt < 2; ++rt)
#pragma unroll
        for (int c4 = 0; c4 < 4; ++c4)
          acc[rt][cg*4 + c4] = __builtin_amdgcn_mfma_f32_16x16x32_bf16(
              a[rt], bq[c4], acc[rt][cg*4 + c4], 0, 0, 0);
    }
  }
  __syncthreads();

#pragma unroll
  for (int rt = 0; rt < 2; ++rt) {
    int ebase = w4*32 + rt*16 + lk*4;
#pragma unroll
    for (int ct = 0; ct < 8; ++ct) {
      int c = ct*16 + lrow;
      Tw[(ebase+0)*128 + c] = (unsigned short)rne16(acc[rt][ct][0]);
      Tw[(ebase+1)*128 + c] = (unsigned short)rne16(acc[rt][ct][1]);
      Tw[(ebase+2)*128 + c] = (unsigned short)rne16(acc[rt][ct][2]);
      Tw[(ebase+3)*128 + c] = (unsigned short)rne16(acc[rt][ct][3]);
    }
  }
  __syncthreads();

  {
    float4 u0 = *(const float4*)&ub[tx*8];
    float4 u1 = *(const float4*)&ub[tx*8+4];
    float ubv[8] = {u0.x,u0.y,u0.z,u0.w,u1.x,u1.y,u1.z,u1.w};
#pragma unroll
    for (int i = 0; i < 8; ++i) {
      int row = ty*8 + i;
      uint4 uv = *(const uint4*)&Tw[row * 128 + tx*8];
      float uvv[8] = {blo(uv.x),bhi(uv.x),blo(uv.y),bhi(uv.y),
                      blo(uv.z),bhi(uv.z),blo(uv.w),bhi(uv.w)};
      float hvv[8] = {blo(hv[i].x),bhi(hv[i].x),blo(hv[i].y),bhi(hv[i].y),
                      blo(hv[i].z),bhi(hv[i].z),blo(hv[i].w),bhi(hv[i].w)};
      float p[8];
#pragma unroll
      for (int j = 0; j < 8; ++j) {
        float v = uvv[j] + hvv[j] + ubv[j];
        p[j] = v > 0.f ? v : 0.f;
      }
      uint4 w;
      w.x = pk2(p[0], p[1]); w.y = pk2(p[2], p[3]);
      w.z = pk2(p[4], p[5]); w.w = pk2(p[6], p[7]);
      *(uint4*)&Tw[row * 128 + tx*8] = w;
    }
  }
  __syncthreads();

  {
    const int nseg = sScal[3];
    const int dprev = sScal[0], dnext = sScal[1];
    for (int s = w4; s < nseg; s += 4) {
      int dst = segdst[s];
      if (dst < 0) continue;
      int r0 = segstart[s];
      int r1 = (s + 1 < nseg) ? segstart[s + 1] : 128;
      float sx = 0.f, sy = 0.f;
      for (int rr = r0; rr < r1; ++rr) {
        unsigned v = *(const unsigned*)&Tw[rr * 128 + lane * 2];
        sx += blo(v); sy += bhi(v);
      }
      float* pp = &Pagg[(size_t)dst * HD + lane * 2];
      if (dst == dprev || dst == dnext) {
        atomicAdd(pp, sx);
        atomicAdd(pp + 1, sy);
      } else {
        float2 st = {sx, sy};
        *(float2*)pp = st;
      }
    }
  }
}

// ---- readout phase 1 --------------------------------------------------------
__global__ __launch_bounds__(256, 4) void readout1_k(
    const unsigned short* __restrict__ hH, const float* __restrict__ l1w,
    const float* __restrict__ l1b, const float* __restrict__ l2w,
    const float* __restrict__ l2b, float* __restrict__ ybuf, int n)
{
  __shared__ __align__(16) unsigned short Bh[8192];
  const int tid = threadIdx.x;
  const int lane = tid & 63, w4 = tid >> 6;
  const int lrow = lane & 15, lk = lane >> 4;
  const int m0 = blockIdx.x * 128;

  for (int it = 0; it < 4; ++it) {
    int g = tid + it * 256;
    int kt = g >> 8, ct = (g >> 6) & 3, ln = g & 63;
    int row = kt * 32 + ((ln >> 4) << 3);
    int col = ct * 16 + (ln & 15);
    unsigned short h8[8];
#pragma unroll
    for (int e = 0; e < 8; ++e) h8[e] = (unsigned short)rne16(l1w[(size_t)(row + e) * 64 + col]);
    uint4 p = {(unsigned)h8[0] | ((unsigned)h8[1] << 16),
               (unsigned)h8[2] | ((unsigned)h8[3] << 16),
               (unsigned)h8[4] | ((unsigned)h8[5] << 16),
               (unsigned)h8[6] | ((unsigned)h8[7] << 16)};
    *(uint4*)&Bh[g * 8] = p;
  }
  __syncthreads();

  f32x4 acc[2][4];
#pragma unroll
  for (int rt = 0; rt < 2; ++rt)
#pragma unroll
    for (int ct = 0; ct < 4; ++ct) acc[rt][ct] = (f32x4){0.f, 0.f, 0.f, 0.f};

#pragma unroll
  for (int kt = 0; kt < 4; ++kt) {
    int k0 = kt * 32 + lk * 8;
    bf16x8 a[2];
#pragma unroll
    for (int rt = 0; rt < 2; ++rt) {
      int row = m0 + w4 * 32 + rt * 16 + lrow;
      if (row < n) a[rt] = *(const bf16x8*)&hH[(size_t)row * HD + k0];
      else a[rt] = (bf16x8){0,0,0,0,0,0,0,0};
    }
#pragma unroll
    for (int ct = 0; ct < 4; ++ct) {
      bf16x8 b = *(const bf16x8*)&Bh[(((kt * 4 + ct) * 64) + lane) * 8];
#pragma unroll
      for (int rt = 0; rt < 2; ++rt)
        acc[rt][ct] = __builtin_amdgcn_mfma_f32_16x16x32_bf16(a[rt], b, acc[rt][ct], 0, 0, 0);
    }
  }

  const float l2b0 = l2b[0];
#pragma unroll
  for (int rt = 0; rt < 2; ++rt) {
    float yp[4] = {0.f, 0.f, 0.f, 0.f};
#pragma unroll
    for (int ct = 0; ct < 4; ++ct) {
      int col = ct * 16 + lrow;
      float b1 = l1b[col], w2 = l2w[col];
#pragma unroll
      for (int reg = 0; reg < 4; ++reg) {
        float z = acc[rt][ct][reg] + b1;
        yp[reg] = fmaf(z > 0.f ? z : 0.f, w2, yp[reg]);
      }
    }
#pragma unroll
    for (int reg = 0; reg < 4; ++reg) {
#pragma unroll
      for (int off = 1; off < 16; off <<= 1) yp[reg] += __shfl_xor(yp[reg], off);
      int row = m0 + w4 * 32 + rt * 16 + lk * 4 + reg;
      if (lrow == 0 && row < n) ybuf[row] = yp[reg] + l2b0;
    }
  }
}

// ---- readout phase 2 --------------------------------------------------------
__global__ void readout2_k(const float* __restrict__ ybuf, const int* __restrict__ batch,
                           float* __restrict__ out, int n) {
  int t = blockIdx.x * 256 + threadIdx.x;
  int base = t * 8;
  if (base >= n) return;
  int bprev = batch[base];
  float s = ybuf[base];
  for (int i = 1; i < 8; ++i) {
    int idx = base + i;
    if (idx >= n) break;
    int bb = batch[idx];
    if (bb != bprev) { atomicAdd(&out[bprev], s); s = 0.f; bprev = bb; }
    s += ybuf[idx];
  }
  atomicAdd(&out[bprev], s);
}

extern "C" void kernel_launch(void* const* d_in, const int* in_sizes, int n_in,
                              void* d_out, int out_size, void* d_ws, size_t ws_size,
                              hipStream_t stream) {
  const float* x     = (const float*)d_in[0];
  const float* pos   = (const float*)d_in[1];
  const int*   ei    = (const int*)d_in[2];
  const int*   batch = (const int*)d_in[3];
  const float* nw1   = (const float*)d_in[4];
  const float* nb1   = (const float*)d_in[5];
  const float* nw2   = (const float*)d_in[6];
  const float* nb2   = (const float*)d_in[7];
  const float* m1w1  = (const float*)d_in[8];
  const float* m1b1  = (const float*)d_in[9];
  const float* m1w2  = (const float*)d_in[10];
  const float* m1b2  = (const float*)d_in[11];
  const float* m2w1  = (const float*)d_in[12];
  const float* m2b1  = (const float*)d_in[13];
  const float* m2w2  = (const float*)d_in[14];
  const float* m2b2  = (const float*)d_in[15];
  const float* m3w1  = (const float*)d_in[16];
  const float* m3b1  = (const float*)d_in[17];
  const float* m3w2  = (const float*)d_in[18];
  const float* m3b2  = (const float*)d_in[19];
  const float* l1w   = (const float*)d_in[20];
  const float* l1b   = (const float*)d_in[21];
  const float* l2w   = (const float*)d_in[22];
  const float* l2b   = (const float*)d_in[23];

  const int N = in_sizes[0];
  const int E = in_sizes[2] / 2;
  const int L = in_sizes[8] / (256 * 128);

  float* Pagg = (float*)d_ws;                                   // [N,128] f32
  unsigned int* spk = (unsigned int*)(Pagg + (size_t)N * HD);   // [E]
  int*   cnt  = (int*)(spk + E);                                // [N]
  float* invd = (float*)(cnt + N);                              // [N]
  float* Wf   = invd + N;                                       // [L,128,128]
  float* ub   = Wf + (size_t)L * 128 * 128;                     // [L,128]
  float* Wm   = ub + (size_t)L * 128;                           // [L,128,128]
  float* bfold= Wm + (size_t)L * 128 * 128;                     // [L,128]
  unsigned short* hAb = (unsigned short*)(bfold + (size_t)L * 128);  // [N,128]
  unsigned short* Wpk = hAb + (size_t)N * HD;                   // [L,16384]
  float* ybuf = (float*)(Wpk + (size_t)L * 16384);              // [N]
  int*   bsum = (int*)(ybuf + N);                               // [128]
  unsigned short* WnBase = (unsigned short*)(bsum + 128);
  unsigned short* WnInit = WnBase;
  unsigned short* WnW2a[3], *WnCat[3], *WnW2[3];
  unsigned short* planes;
  {
    unsigned short* p = WnBase + 32768;
    for (int l = 0; l < 3; ++l) {
      WnW2a[l] = p; p += 32768;
      WnCat[l] = p; p += 65536;
      WnW2[l]  = p; p += 32768;
    }
    planes = p;
  }
  unsigned short* hH = planes;                 // [N,128]
  unsigned short* hL = hH + (size_t)N * HD;

  hipMemsetAsync(cnt, 0, (size_t)N * sizeof(int), stream);
  hipMemsetAsync(d_out, 0, (size_t)out_size * sizeof(float), stream);

  count_k<<<(E + 255) / 256, 256, 0, stream>>>(ei, cnt, E);
  const int nsb = (N + 511) / 512;
  scanA_k<<<nsb, 512, 0, stream>>>(cnt, bsum, N);
  scanB_k<<<1, 128, 0, stream>>>(bsum, nsb);
  scanC_k<<<nsb, 512, 0, stream>>>(cnt, invd, bsum, N);
  scatter_k<<<(E + 255) / 256, 256, 0, stream>>>(ei, cnt, spk, E);
  fold_all_k<<<dim3(128, L, 2), 128, 0, stream>>>(m3w2, m2w1, m3b2, m2b1,
                                                  m2w2, m1w1, m2b2, Wf, ub, Wm, bfold);
  pack_k<<<dim3(64, L), 256, 0, stream>>>(Wf, Wpk);

  {
    PArgs pa;
    pa.d[0] = {nw2, nullptr, WnInit, 4};
    for (int l = 0; l < L; ++l) {
      pa.d[1 + l * 3] = {m2w1 + (size_t)l * 256 * 128, nullptr, WnW2a[l], 4};
      pa.d[2 + l * 3] = {Wm + (size_t)l * 128 * 128,
                         m1w1 + (size_t)l * 256 * 128 + 128 * 128, WnCat[l], 8};
      pa.d[3 + l * 3] = {m1w2 + (size_t)l * 128 * 128, nullptr, WnW2[l], 4};
    }
    packw_k<<<dim3(128, 1 + L * 3), 256, 0, stream>>>(pa);
  }

  const int gblk = (N + 63) / 64;
  // h0 = relu(x*nw1+nb1)@nw2+nb2 -> planes ; fused hAb = bf16(h0) @ W2a[0]
  init_k<<<gblk, 256, 0, stream>>>(x, WnInit, nb2, nw1, nb1, hH, hL, WnW2a[0], hAb, N);

  const int nwg = (E + 127) / 128;
  const int nbz = ((nwg - 1) * 32 + 255) / 256;
  for (int l = 0; l < L; ++l) {
    bzero_k<<<nbz, 256, 0, stream>>>(spk, Pagg, nwg);
    edge_k<<<nwg, 256, 0, stream>>>(
        spk, pos, hAb,
        m3w1 + (size_t)l * 3 * 128, m3b1 + (size_t)l * 128,
        Wpk + (size_t)l * 16384, ub + (size_t)l * 128,
        Pagg, E, nwg);
    if (l + 1 < L) {
      layer_k<false><<<gblk, 256, 0, stream>>>(
          Pagg, hH, hL, invd, WnCat[l], m1b1 + (size_t)l * 128,
          bfold + (size_t)l * 128, WnW2[l], m1b2 + (size_t)l * 128,
          WnW2a[l + 1], hH, hL, hAb, N);
    } else {
      layer_k<true><<<gblk, 256, 0, stream>>>(
          Pagg, hH, hL, invd, WnCat[l], m1b1 + (size_t)l * 128,
          bfold + (size_t)l * 128, WnW2[l], m1b2 + (size_t)l * 128,
          nullptr, hH, hL, nullptr, N);
    }
  }

  readout1_k<<<(N + 127) / 128, 256, 0, stream>>>(hH, l1w, l1b, l2w, l2b, ybuf, N);
  readout2_k<<<(N + 2047) / 2048, 256, 0, stream>>>(ybuf, batch, (float*)d_out, N);
}

// Round 11
// 703.506 us; speedup vs baseline: 1.0458x; 1.0096x over previous
//
#include <hip/hip_runtime.h>

#define HD 128

typedef __attribute__((ext_vector_type(8))) short bf16x8;
typedef __attribute__((ext_vector_type(4))) float f32x4;

// ---- bf16 helpers ----------------------------------------------------------
__device__ __forceinline__ unsigned rne16(float x) {
  unsigned u = __builtin_bit_cast(unsigned, x);
  return (u + 0x7fffu + ((u >> 16) & 1u)) >> 16;
}
__device__ __forceinline__ unsigned pk2(float a, float b) {  // HW v_cvt_pk_bf16_f32
  unsigned r;
  asm("v_cvt_pk_bf16_f32 %0, %1, %2" : "=v"(r) : "v"(a), "v"(b));
  return r;
}
__device__ __forceinline__ float blo(unsigned u) { return __builtin_bit_cast(float, u << 16); }
__device__ __forceinline__ float bhi(unsigned u) { return __builtin_bit_cast(float, u & 0xffff0000u); }
__device__ __forceinline__ float bval(unsigned h16) { return __builtin_bit_cast(float, h16 << 16); }

__device__ __forceinline__ void bsplit(float v, unsigned short& hi, unsigned short& lo) {
  unsigned h = rne16(v);
  hi = (unsigned short)h;
  lo = (unsigned short)rne16(v - bval(h));
}
__device__ __forceinline__ void bsplit2(float v0, float v1, unsigned& hi, unsigned& lo) {
  hi = pk2(v0, v1);
  lo = pk2(v0 - bval(hi & 0xffffu), v1 - bval(hi >> 16));
}
__device__ __forceinline__ int swzc(int col, int lr) {
  return (((col >> 3) ^ (lr & 7)) << 3) | (col & 7);
}

// ---- degree count ----------------------------------------------------------
__global__ void count_k(const int* __restrict__ ei, int* __restrict__ cnt, int E) {
  int e = blockIdx.x * 256 + threadIdx.x;
  if (e < E) atomicAdd(&cnt[ei[E + e]], 1);
}

// ---- 3-phase multi-block exclusive scan ------------------------------------
__global__ __launch_bounds__(512) void scanA_k(const int* __restrict__ cnt,
                                               int* __restrict__ bsum, int n) {
  __shared__ int ws[8];
  const int tid = threadIdx.x, lane = tid & 63, wid = tid >> 6;
  int i = blockIdx.x * 512 + tid;
  int v = (i < n) ? cnt[i] : 0;
#pragma unroll
  for (int off = 32; off > 0; off >>= 1) v += __shfl_xor(v, off);
  if (lane == 0) ws[wid] = v;
  __syncthreads();
  if (tid == 0) {
    int s = 0;
#pragma unroll
    for (int w = 0; w < 8; ++w) s += ws[w];
    bsum[blockIdx.x] = s;
  }
}

__global__ __launch_bounds__(128) void scanB_k(int* __restrict__ bsum, int nb) {
  __shared__ int w2[2];
  const int tid = threadIdx.x, lane = tid & 63, wid = tid >> 6;
  int v = (tid < nb) ? bsum[tid] : 0;
  int s = v;
#pragma unroll
  for (int off = 1; off < 64; off <<= 1) {
    int u = __shfl_up(s, off);
    if (lane >= off) s += u;
  }
  if (lane == 63) w2[wid] = s;
  __syncthreads();
  int add = (wid == 1) ? w2[0] : 0;
  if (tid < nb) bsum[tid] = s - v + add;
}

__global__ __launch_bounds__(512) void scanC_k(int* __restrict__ cnt, float* __restrict__ invd,
                                               const int* __restrict__ bsum, int n) {
  __shared__ int ws[8];
  const int tid = threadIdx.x, lane = tid & 63, wid = tid >> 6;
  int i = blockIdx.x * 512 + tid;
  int v = (i < n) ? cnt[i] : 0;
  int s = v;
#pragma unroll
  for (int off = 1; off < 64; off <<= 1) {
    int u = __shfl_up(s, off);
    if (lane >= off) s += u;
  }
  if (lane == 63) ws[wid] = s;
  __syncthreads();
  int wadd = 0;
  for (int w = 0; w < wid; ++w) wadd += ws[w];
  if (i < n) {
    cnt[i] = s - v + wadd + bsum[blockIdx.x];
    invd[i] = v > 0 ? 1.f / (float)v : 0.f;
  }
}

// ---- scatter into dst-sorted order -----------------------------------------
__global__ void scatter_k(const int* __restrict__ ei, int* __restrict__ cur,
                          unsigned int* __restrict__ spk, int E) {
  int e = blockIdx.x * 256 + threadIdx.x;
  if (e >= E) return;
  int s = ei[e], d = ei[E + e];
  int p = atomicAdd(&cur[d], 1);
  spk[p] = (unsigned int)s | ((unsigned int)d << 16);
}

// ---- weight folding --------------------------------------------------------
__global__ void fold_all_k(const float* __restrict__ m3w2, const float* __restrict__ m2w1,
                           const float* __restrict__ m3b2, const float* __restrict__ m2b1,
                           const float* __restrict__ m2w2, const float* __restrict__ m1w1,
                           const float* __restrict__ m2b2,
                           float* __restrict__ Wf, float* __restrict__ ub,
                           float* __restrict__ Wm, float* __restrict__ bf) {
  const int k = blockIdx.x, l = blockIdx.y, mode = blockIdx.z, c = threadIdx.x;
  const float *A, *B, *bA, *badd;
  float *O, *ob;
  if (mode == 0) {
    A = m3w2 + (size_t)l * 128 * 128;
    B = m2w1 + (size_t)l * 256 * 128 + 128 * 128;
    bA = m3b2 + (size_t)l * 128; badd = m2b1 + (size_t)l * 128;
    O = Wf + (size_t)l * 128 * 128; ob = ub + (size_t)l * 128;
  } else {
    A = m2w2 + (size_t)l * 128 * 128;
    B = m1w1 + (size_t)l * 256 * 128;
    bA = m2b2 + (size_t)l * 128; badd = nullptr;
    O = Wm + (size_t)l * 128 * 128; ob = bf + (size_t)l * 128;
  }
  float s = 0.f;
  for (int r = 0; r < 128; ++r) s = fmaf(A[k * 128 + r], B[r * 128 + c], s);
  O[k * 128 + c] = s;
  if (k == 0) {
    float t = badd ? badd[c] : 0.f;
    for (int r = 0; r < 128; ++r) t = fmaf(bA[r], B[r * 128 + c], t);
    ob[c] = t;
  }
}

// ---- pack Wf into bf16 B-fragment order (edge kernel, hi only) -------------
__global__ void pack_k(const float* __restrict__ Wf, unsigned short* __restrict__ Wpk) {
  int l = blockIdx.y;
  int flat = blockIdx.x * 256 + threadIdx.x;
  int e = flat & 7, l6 = (flat >> 3) & 63, ct = (flat >> 9) & 7, kt = flat >> 12;
  int row = kt * 32 + ((l6 >> 4) << 3) + e;
  int col = ct * 16 + (l6 & 15);
  Wpk[(size_t)l * 16384 + flat] =
      (unsigned short)rne16(Wf[(size_t)l * 16384 + row * 128 + col]);
}

// ---- pack node-GEMM weights into hi/lo B-fragment buffers ------------------
struct PDesc { const float* w0; const float* w1; unsigned short* out; int kt; };
struct PArgs { PDesc d[10]; };

__global__ void packw_k(PArgs pa) {
  PDesc de = pa.d[blockIdx.y];
  int flat = blockIdx.x * 256 + threadIdx.x;
  int tot = de.kt * 4096;
  if (flat >= tot) return;
  int e = flat & 7, ln = (flat >> 3) & 63, ct = (flat >> 9) & 7, kt = flat >> 12;
  int row = kt * 32 + ((ln >> 4) << 3) + e;
  int col = ct * 16 + (ln & 15);
  float v = (row < 128) ? de.w0[(size_t)row * 128 + col]
                        : de.w1[(size_t)(row - 128) * 128 + col];
  unsigned short hi, lo;
  bsplit(v, hi, lo);
  de.out[flat] = hi;
  de.out[tot + flat] = lo;
}

// ---- init GEMM: h = relu(x*aw+ab) @ Wn + bias -> planes ; fused hAb --------
__global__ __launch_bounds__(256) void init_k(
    const float* __restrict__ x, const unsigned short* __restrict__ Wn,
    const float* __restrict__ bias, const float* __restrict__ aw,
    const float* __restrict__ ab,
    unsigned short* __restrict__ outh, unsigned short* __restrict__ outl,
    const unsigned short* __restrict__ Wa, unsigned short* __restrict__ outA, int M)
{
  __shared__ __align__(16) unsigned short hT[64 * 128];
  const int tid = threadIdx.x;
  const int lane = tid & 63, w4 = tid >> 6;
  const int lrow = lane & 15, lk = lane >> 4;
  const int m0 = blockIdx.x * 64;
  const unsigned short* __restrict__ Wlo = Wn + 16384;

  const int rown = m0 + w4 * 16 + lrow;
  const bool valid = rown < M;
  const float xv = valid ? x[rown] : 0.f;

  f32x4 acc[8];
#pragma unroll
  for (int ct = 0; ct < 8; ++ct) acc[ct] = (f32x4){0.f, 0.f, 0.f, 0.f};

#pragma unroll
  for (int ktg = 0; ktg < 4; ++ktg) {
    const int k0 = ktg * 32 + lk * 8;
    float4 a0 = *(const float4*)&aw[k0];
    float4 a1 = *(const float4*)&aw[k0 + 4];
    float4 b0 = *(const float4*)&ab[k0];
    float4 b1 = *(const float4*)&ab[k0 + 4];
    float awv[8] = {a0.x,a0.y,a0.z,a0.w,a1.x,a1.y,a1.z,a1.w};
    float abv[8] = {b0.x,b0.y,b0.z,b0.w,b1.x,b1.y,b1.z,b1.w};
    unsigned h4[4], l4[4];
#pragma unroll
    for (int e = 0; e < 4; ++e) {
      float v0 = fmaf(xv, awv[e*2], abv[e*2]);
      float v1 = fmaf(xv, awv[e*2+1], abv[e*2+1]);
      v0 = v0 > 0.f ? v0 : 0.f;
      v1 = v1 > 0.f ? v1 : 0.f;
      bsplit2(v0, v1, h4[e], l4[e]);
    }
    bf16x8 ah = __builtin_bit_cast(bf16x8, *(uint4*)h4);
    bf16x8 al = __builtin_bit_cast(bf16x8, *(uint4*)l4);
#pragma unroll
    for (int ct = 0; ct < 8; ++ct) {
      const size_t boff = (size_t)(((ktg * 8 + ct) * 64) + lane) * 8;
      bf16x8 bh = *(const bf16x8*)&Wn[boff];
      bf16x8 bl = *(const bf16x8*)&Wlo[boff];
      acc[ct] = __builtin_amdgcn_mfma_f32_16x16x32_bf16(ah, bh, acc[ct], 0, 0, 0);
      acc[ct] = __builtin_amdgcn_mfma_f32_16x16x32_bf16(al, bh, acc[ct], 0, 0, 0);
      acc[ct] = __builtin_amdgcn_mfma_f32_16x16x32_bf16(ah, bl, acc[ct], 0, 0, 0);
    }
  }

  const int rbl = w4 * 16 + lk * 4;
#pragma unroll
  for (int ct = 0; ct < 8; ++ct) {
    int col = ct * 16 + lrow;
    float bv = bias[col];
#pragma unroll
    for (int reg = 0; reg < 4; ++reg) {
      int row = m0 + rbl + reg;
      if (row < M) {
        float v = acc[ct][reg] + bv;
        unsigned short hi, lo;
        bsplit(v, hi, lo);
        outh[(size_t)row * HD + col] = hi;
        outl[(size_t)row * HD + col] = lo;
        hT[(rbl + reg) * 128 + swzc(col, rbl + reg)] = hi;
      }
    }
  }

  // fused hAb = h_hi @ Wa  (wave-local rows, no barrier)
  const unsigned short* __restrict__ Walo = Wa + 16384;
  f32x4 ac2[8];
#pragma unroll
  for (int ct = 0; ct < 8; ++ct) ac2[ct] = (f32x4){0.f, 0.f, 0.f, 0.f};
#pragma unroll
  for (int ktg = 0; ktg < 4; ++ktg) {
    const int lr = w4 * 16 + lrow;
    const int kb = ktg * 4 + lk;
    bf16x8 a = *(const bf16x8*)&hT[lr * 128 + ((kb ^ (lr & 7)) << 3)];
#pragma unroll
    for (int ct = 0; ct < 8; ++ct) {
      const size_t boff = (size_t)(((ktg * 8 + ct) * 64) + lane) * 8;
      bf16x8 bh = *(const bf16x8*)&Wa[boff];
      bf16x8 bl = *(const bf16x8*)&Walo[boff];
      ac2[ct] = __builtin_amdgcn_mfma_f32_16x16x32_bf16(a, bh, ac2[ct], 0, 0, 0);
      ac2[ct] = __builtin_amdgcn_mfma_f32_16x16x32_bf16(a, bl, ac2[ct], 0, 0, 0);
    }
  }
#pragma unroll
  for (int ct = 0; ct < 8; ++ct) {
    int col = ct * 16 + lrow;
#pragma unroll
    for (int reg = 0; reg < 4; ++reg) {
      int row = m0 + rbl + reg;
      if (row < M) outA[(size_t)row * HD + col] = (unsigned short)rne16(ac2[ct][reg]);
    }
  }
}

// ---- fused layer kernel: cat-GEMM -> w2-GEMM -> (hAb GEMM) -----------------
template<bool LAST>
__global__ __launch_bounds__(256) void layer_k(
    const float* __restrict__ Pagg,
    const unsigned short* __restrict__ hH, const unsigned short* __restrict__ hL,
    const float* __restrict__ invd,
    const unsigned short* __restrict__ Wcat, const float* __restrict__ b1,
    const float* __restrict__ bf,
    const unsigned short* __restrict__ W2, const float* __restrict__ b2,
    const unsigned short* __restrict__ Wa,
    unsigned short* __restrict__ hHo, unsigned short* __restrict__ hLo,
    unsigned short* __restrict__ outA, int M)
{
  __shared__ __align__(16) unsigned short tmpH[64 * 128];
  __shared__ __align__(16) unsigned short tmpL[64 * 128];
  const int tid = threadIdx.x;
  const int lane = tid & 63, w4 = tid >> 6;
  const int lrow = lane & 15, lk = lane >> 4;
  const int m0 = blockIdx.x * 64;

  const int rown = m0 + w4 * 16 + lrow;
  const bool valid = rown < M;
  const float scl = valid ? invd[rown] : 0.f;

  const unsigned short* __restrict__ Wclo = Wcat + 32768;
  f32x4 acc[8];
#pragma unroll
  for (int ct = 0; ct < 8; ++ct) acc[ct] = (f32x4){0.f, 0.f, 0.f, 0.f};

#pragma unroll
  for (int ktg = 0; ktg < 8; ++ktg) {
    const int k0 = ktg * 32 + lk * 8;
    bf16x8 ah, al;
    if (k0 >= 128) {
      if (valid) {
        ah = *(const bf16x8*)&hH[(size_t)rown * HD + (k0 - 128)];
        al = *(const bf16x8*)&hL[(size_t)rown * HD + (k0 - 128)];
      } else {
        ah = (bf16x8){0,0,0,0,0,0,0,0};
        al = (bf16x8){0,0,0,0,0,0,0,0};
      }
    } else {
      float v[8] = {0,0,0,0,0,0,0,0};
      if (valid) {
        const float* base = Pagg + (size_t)rown * HD + k0;
        float4 v0 = *(const float4*)base;
        float4 v1 = *(const float4*)(base + 4);
        v[0]=v0.x*scl; v[1]=v0.y*scl; v[2]=v0.z*scl; v[3]=v0.w*scl;
        v[4]=v1.x*scl; v[5]=v1.y*scl; v[6]=v1.z*scl; v[7]=v1.w*scl;
      }
      unsigned h4[4], l4[4];
#pragma unroll
      for (int e = 0; e < 4; ++e) bsplit2(v[e*2], v[e*2+1], h4[e], l4[e]);
      ah = __builtin_bit_cast(bf16x8, *(uint4*)h4);
      al = __builtin_bit_cast(bf16x8, *(uint4*)l4);
    }
#pragma unroll
    for (int ct = 0; ct < 8; ++ct) {
      const size_t boff = (size_t)(((ktg * 8 + ct) * 64) + lane) * 8;
      bf16x8 bh = *(const bf16x8*)&Wcat[boff];
      bf16x8 bl = *(const bf16x8*)&Wclo[boff];
      acc[ct] = __builtin_amdgcn_mfma_f32_16x16x32_bf16(ah, bh, acc[ct], 0, 0, 0);
      acc[ct] = __builtin_amdgcn_mfma_f32_16x16x32_bf16(al, bh, acc[ct], 0, 0, 0);
      acc[ct] = __builtin_amdgcn_mfma_f32_16x16x32_bf16(ah, bl, acc[ct], 0, 0, 0);
    }
  }

  const int rbl = w4 * 16 + lk * 4;
  float m2[4];
#pragma unroll
  for (int reg = 0; reg < 4; ++reg) {
    int row = m0 + rbl + reg;
    m2[reg] = (row < M && invd[row] > 0.f) ? 1.f : 0.f;
  }
#pragma unroll
  for (int ct = 0; ct < 8; ++ct) {
    int col = ct * 16 + lrow;
    float bv = b1[col], bfv = bf[col];
#pragma unroll
    for (int reg = 0; reg < 4; ++reg) {
      int lr = rbl + reg;
      float v = acc[ct][reg] + bv + m2[reg] * bfv;
      if (v < 0.f) v = 0.f;
      unsigned short hi, lo;
      bsplit(v, hi, lo);
      int sp = lr * 128 + swzc(col, lr);
      tmpH[sp] = hi;
      tmpL[sp] = lo;
    }
  }

  const unsigned short* __restrict__ W2lo = W2 + 16384;
  f32x4 ac2[8];
#pragma unroll
  for (int ct = 0; ct < 8; ++ct) ac2[ct] = (f32x4){0.f, 0.f, 0.f, 0.f};
#pragma unroll
  for (int ktg = 0; ktg < 4; ++ktg) {
    const int lr = w4 * 16 + lrow;
    const int off = lr * 128 + (((ktg * 4 + lk) ^ (lr & 7)) << 3);
    bf16x8 aH = *(const bf16x8*)&tmpH[off];
    bf16x8 aL = *(const bf16x8*)&tmpL[off];
#pragma unroll
    for (int ct = 0; ct < 8; ++ct) {
      const size_t boff = (size_t)(((ktg * 8 + ct) * 64) + lane) * 8;
      bf16x8 bh = *(const bf16x8*)&W2[boff];
      bf16x8 bl = *(const bf16x8*)&W2lo[boff];
      ac2[ct] = __builtin_amdgcn_mfma_f32_16x16x32_bf16(aH, bh, ac2[ct], 0, 0, 0);
      ac2[ct] = __builtin_amdgcn_mfma_f32_16x16x32_bf16(aL, bh, ac2[ct], 0, 0, 0);
      ac2[ct] = __builtin_amdgcn_mfma_f32_16x16x32_bf16(aH, bl, ac2[ct], 0, 0, 0);
    }
  }
#pragma unroll
  for (int ct = 0; ct < 8; ++ct) {
    int col = ct * 16 + lrow;
    float bv = b2[col];
#pragma unroll
    for (int reg = 0; reg < 4; ++reg) {
      int row = m0 + rbl + reg;
      if (row < M) {
        float v = ac2[ct][reg] + bv;
        if (v < 0.f) v = 0.f;
        unsigned short hi, lo;
        bsplit(v, hi, lo);
        hHo[(size_t)row * HD + col] = hi;
        hLo[(size_t)row * HD + col] = lo;
        if (!LAST) {
          int lr = rbl + reg;
          tmpL[lr * 128 + swzc(col, lr)] = hi;
        }
      }
    }
  }

  if constexpr (!LAST) {
    const unsigned short* __restrict__ Walo = Wa + 16384;
    f32x4 ac3[8];
#pragma unroll
    for (int ct = 0; ct < 8; ++ct) ac3[ct] = (f32x4){0.f, 0.f, 0.f, 0.f};
#pragma unroll
    for (int ktg = 0; ktg < 4; ++ktg) {
      const int lr = w4 * 16 + lrow;
      bf16x8 a = *(const bf16x8*)&tmpL[lr * 128 + (((ktg * 4 + lk) ^ (lr & 7)) << 3)];
#pragma unroll
      for (int ct = 0; ct < 8; ++ct) {
        const size_t boff = (size_t)(((ktg * 8 + ct) * 64) + lane) * 8;
        bf16x8 bh = *(const bf16x8*)&Wa[boff];
        bf16x8 bl = *(const bf16x8*)&Walo[boff];
        ac3[ct] = __builtin_amdgcn_mfma_f32_16x16x32_bf16(a, bh, ac3[ct], 0, 0, 0);
        ac3[ct] = __builtin_amdgcn_mfma_f32_16x16x32_bf16(a, bl, ac3[ct], 0, 0, 0);
      }
    }
#pragma unroll
    for (int ct = 0; ct < 8; ++ct) {
      int col = ct * 16 + lrow;
#pragma unroll
      for (int reg = 0; reg < 4; ++reg) {
        int row = m0 + rbl + reg;
        if (row < M) outA[(size_t)row * HD + col] = (unsigned short)rne16(ac3[ct][reg]);
      }
    }
  }
}

// ---- zero Pagg rows that receive atomics (64-edge blocks) ------------------
__global__ void bzero_k(const unsigned int* __restrict__ spk, float* __restrict__ Pagg,
                        int nwg) {
  int g = blockIdx.x * 256 + threadIdx.x;
  int idx = g >> 5, l32 = g & 31;
  if (idx >= nwg - 1) return;
  int dst = (int)(spk[(idx + 1) * 64] >> 16);
  *(float4*)&Pagg[(size_t)dst * HD + l32 * 4] = (float4){0.f, 0.f, 0.f, 0.f};
}

// ---- fused edge kernel: 64 edges/block, t in registers, 2 barriers ---------
__global__ __launch_bounds__(256, 6) void edge_k(
    const unsigned int* __restrict__ spk, const float* __restrict__ pos,
    const unsigned short* __restrict__ hAb,
    const float* __restrict__ w31, const float* __restrict__ b31,
    const unsigned short* __restrict__ Wpk, const float* __restrict__ ub,
    float* __restrict__ Pagg, int E, int nwg)
{
  __shared__ __align__(16) unsigned short Tw[64 * 128];  // u then P
  __shared__ int SD[64];
  __shared__ int segstart[68];
  __shared__ int segdst[68];
  __shared__ int sScal[4];
  const int tid = threadIdx.x;
  const int lane = tid & 63, w4 = tid >> 6;
  const int lrow = lane & 15, lk = lane >> 4;

  int b = blockIdx.x;
  int q = nwg >> 3, r = nwg & 7;
  int xcd = b & 7, sub = b >> 3;
  int wg = (xcd < r ? xcd * (q + 1) : r * (q + 1) + (xcd - r) * q) + sub;
  const int e0 = wg * 64;

  // ---- stage 1 (registers only): own edge, dist, t-fragments ----
  const int myedge = e0 + w4 * 16 + lrow;
  int d = -1;
  float d0 = 0.f, d1 = 0.f, d2 = 0.f;
  if (myedge < E) {
    unsigned pk = spk[myedge];
    int s = (int)(pk & 0xffffu);
    d = (int)(pk >> 16);
    d0 = pos[(size_t)s*3+0] - pos[(size_t)d*3+0];
    d1 = pos[(size_t)s*3+1] - pos[(size_t)d*3+1];
    d2 = pos[(size_t)s*3+2] - pos[(size_t)d*3+2];
  }
  if (lk == 0) SD[w4 * 16 + lrow] = d;
  if (tid == 0) sScal[0] = (e0 > 0) ? (int)(spk[e0-1] >> 16) : -2;
  if (tid == 1) sScal[1] = (e0 + 64 < E) ? (int)(spk[e0+64] >> 16) : -2;

  bf16x8 ah[4];
#pragma unroll
  for (int kt = 0; kt < 4; ++kt) {
    const int k0 = kt * 32 + lk * 8;
    unsigned h4[4];
#pragma unroll
    for (int e = 0; e < 4; ++e) {
      int k = k0 + e * 2;
      float v0 = fmaf(d0, w31[k],   fmaf(d1, w31[128+k],   fmaf(d2, w31[256+k],   b31[k])));
      float v1 = fmaf(d0, w31[k+1], fmaf(d1, w31[128+k+1], fmaf(d2, w31[256+k+1], b31[k+1])));
      v0 = v0 > 0.f ? v0 : 0.f;
      v1 = v1 > 0.f ? v1 : 0.f;
      h4[e] = pk2(v0, v1);
    }
    ah[kt] = __builtin_bit_cast(bf16x8, *(uint4*)h4);
  }

  // ---- MFMA: u = t @ Wf (K=128, hi only) ----
  f32x4 acc[8];
#pragma unroll
  for (int ct = 0; ct < 8; ++ct) acc[ct] = (f32x4){0.f, 0.f, 0.f, 0.f};
#pragma unroll
  for (int kt = 0; kt < 4; ++kt) {
#pragma unroll
    for (int ct = 0; ct < 8; ++ct) {
      bf16x8 bq = *(const bf16x8*)&Wpk[(size_t)(((kt*8 + ct) * 64) + lane) * 8];
      acc[ct] = __builtin_amdgcn_mfma_f32_16x16x32_bf16(ah[kt], bq, acc[ct], 0, 0, 0);
    }
  }

  // ---- u (bf16) -> Tw as [e][c] ----
  {
    const int ebase = w4 * 16 + lk * 4;
#pragma unroll
    for (int ct = 0; ct < 8; ++ct) {
      int c = ct * 16 + lrow;
      Tw[(ebase+0)*128 + c] = (unsigned short)rne16(acc[ct][0]);
      Tw[(ebase+1)*128 + c] = (unsigned short)rne16(acc[ct][1]);
      Tw[(ebase+2)*128 + c] = (unsigned short)rne16(acc[ct][2]);
      Tw[(ebase+3)*128 + c] = (unsigned short)rne16(acc[ct][3]);
    }
  }

  // ---- issue hA gather (latency hidden by barrier + ballot + P setup) ----
  const int typ = tid >> 4, tx = tid & 15;
  uint4 hv[4];
#pragma unroll
  for (int i = 0; i < 4; ++i) {
    int p = e0 + typ * 4 + i;
    unsigned pk = (p < E) ? spk[p] : 0u;
    hv[i] = *(const uint4*)&hAb[(size_t)(pk & 0xffffu) * HD + tx * 8];
  }
  __syncthreads();   // SD + u complete

  // ---- segment heads: single-wave ballot (wave 0) ----
  if (tid < 64) {
    int dd = SD[tid];
    bool head = (tid == 0) || (dd != SD[tid - 1]);
    unsigned long long bal = __ballot(head);
    int rank = __popcll(bal & ((1ull << lane) - 1));
    if (head) { segstart[rank] = tid; segdst[rank] = dd; }
    if (tid == 0) sScal[3] = __popcll(bal);
  }

  // ---- P = relu(u + hA[src] + ub) in place (bf16) ----
  {
    float4 u0 = *(const float4*)&ub[tx*8];
    float4 u1 = *(const float4*)&ub[tx*8+4];
    float ubv[8] = {u0.x,u0.y,u0.z,u0.w,u1.x,u1.y,u1.z,u1.w};
#pragma unroll
    for (int i = 0; i < 4; ++i) {
      int row = typ * 4 + i;
      uint4 uv = *(const uint4*)&Tw[row * 128 + tx*8];
      float uvv[8] = {blo(uv.x),bhi(uv.x),blo(uv.y),bhi(uv.y),
                      blo(uv.z),bhi(uv.z),blo(uv.w),bhi(uv.w)};
      float hvv[8] = {blo(hv[i].x),bhi(hv[i].x),blo(hv[i].y),bhi(hv[i].y),
                      blo(hv[i].z),bhi(hv[i].z),blo(hv[i].w),bhi(hv[i].w)};
      float p[8];
#pragma unroll
      for (int j = 0; j < 8; ++j) {
        float v = uvv[j] + hvv[j] + ubv[j];
        p[j] = v > 0.f ? v : 0.f;
      }
      uint4 w;
      w.x = pk2(p[0], p[1]); w.y = pk2(p[2], p[3]);
      w.z = pk2(p[4], p[5]); w.w = pk2(p[6], p[7]);
      *(uint4*)&Tw[row * 128 + tx*8] = w;
    }
  }
  __syncthreads();   // P + segment lists complete

  // ---- segment reduce: plain store unless boundary ----
  {
    const int nseg = sScal[3];
    const int dprev = sScal[0], dnext = sScal[1];
    for (int s = w4; s < nseg; s += 4) {
      int dst = segdst[s];
      if (dst < 0) continue;
      int r0 = segstart[s];
      int r1 = (s + 1 < nseg) ? segstart[s + 1] : 64;
      float sx = 0.f, sy = 0.f;
      for (int rr = r0; rr < r1; ++rr) {
        unsigned v = *(const unsigned*)&Tw[rr * 128 + lane * 2];
        sx += blo(v); sy += bhi(v);
      }
      float* pp = &Pagg[(size_t)dst * HD + lane * 2];
      if (dst == dprev || dst == dnext) {
        atomicAdd(pp, sx);
        atomicAdd(pp + 1, sy);
      } else {
        float2 st = {sx, sy};
        *(float2*)pp = st;
      }
    }
  }
}

// ---- readout phase 1 --------------------------------------------------------
__global__ __launch_bounds__(256, 4) void readout1_k(
    const unsigned short* __restrict__ hH, const float* __restrict__ l1w,
    const float* __restrict__ l1b, const float* __restrict__ l2w,
    const float* __restrict__ l2b, float* __restrict__ ybuf, int n)
{
  __shared__ __align__(16) unsigned short Bh[8192];
  const int tid = threadIdx.x;
  const int lane = tid & 63, w4 = tid >> 6;
  const int lrow = lane & 15, lk = lane >> 4;
  const int m0 = blockIdx.x * 128;

  for (int it = 0; it < 4; ++it) {
    int g = tid + it * 256;
    int kt = g >> 8, ct = (g >> 6) & 3, ln = g & 63;
    int row = kt * 32 + ((ln >> 4) << 3);
    int col = ct * 16 + (ln & 15);
    unsigned short h8[8];
#pragma unroll
    for (int e = 0; e < 8; ++e) h8[e] = (unsigned short)rne16(l1w[(size_t)(row + e) * 64 + col]);
    uint4 p = {(unsigned)h8[0] | ((unsigned)h8[1] << 16),
               (unsigned)h8[2] | ((unsigned)h8[3] << 16),
               (unsigned)h8[4] | ((unsigned)h8[5] << 16),
               (unsigned)h8[6] | ((unsigned)h8[7] << 16)};
    *(uint4*)&Bh[g * 8] = p;
  }
  __syncthreads();

  f32x4 acc[2][4];
#pragma unroll
  for (int rt = 0; rt < 2; ++rt)
#pragma unroll
    for (int ct = 0; ct < 4; ++ct) acc[rt][ct] = (f32x4){0.f, 0.f, 0.f, 0.f};

#pragma unroll
  for (int kt = 0; kt < 4; ++kt) {
    int k0 = kt * 32 + lk * 8;
    bf16x8 a[2];
#pragma unroll
    for (int rt = 0; rt < 2; ++rt) {
      int row = m0 + w4 * 32 + rt * 16 + lrow;
      if (row < n) a[rt] = *(const bf16x8*)&hH[(size_t)row * HD + k0];
      else a[rt] = (bf16x8){0,0,0,0,0,0,0,0};
    }
#pragma unroll
    for (int ct = 0; ct < 4; ++ct) {
      bf16x8 b = *(const bf16x8*)&Bh[(((kt * 4 + ct) * 64) + lane) * 8];
#pragma unroll
      for (int rt = 0; rt < 2; ++rt)
        acc[rt][ct] = __builtin_amdgcn_mfma_f32_16x16x32_bf16(a[rt], b, acc[rt][ct], 0, 0, 0);
    }
  }

  const float l2b0 = l2b[0];
#pragma unroll
  for (int rt = 0; rt < 2; ++rt) {
    float yp[4] = {0.f, 0.f, 0.f, 0.f};
#pragma unroll
    for (int ct = 0; ct < 4; ++ct) {
      int col = ct * 16 + lrow;
      float b1 = l1b[col], w2 = l2w[col];
#pragma unroll
      for (int reg = 0; reg < 4; ++reg) {
        float z = acc[rt][ct][reg] + b1;
        yp[reg] = fmaf(z > 0.f ? z : 0.f, w2, yp[reg]);
      }
    }
#pragma unroll
    for (int reg = 0; reg < 4; ++reg) {
#pragma unroll
      for (int off = 1; off < 16; off <<= 1) yp[reg] += __shfl_xor(yp[reg], off);
      int row = m0 + w4 * 32 + rt * 16 + lk * 4 + reg;
      if (lrow == 0 && row < n) ybuf[row] = yp[reg] + l2b0;
    }
  }
}

// ---- readout phase 2 --------------------------------------------------------
__global__ void readout2_k(const float* __restrict__ ybuf, const int* __restrict__ batch,
                           float* __restrict__ out, int n) {
  int t = blockIdx.x * 256 + threadIdx.x;
  int base = t * 8;
  if (base >= n) return;
  int bprev = batch[base];
  float s = ybuf[base];
  for (int i = 1; i < 8; ++i) {
    int idx = base + i;
    if (idx >= n) break;
    int bb = batch[idx];
    if (bb != bprev) { atomicAdd(&out[bprev], s); s = 0.f; bprev = bb; }
    s += ybuf[idx];
  }
  atomicAdd(&out[bprev], s);
}

extern "C" void kernel_launch(void* const* d_in, const int* in_sizes, int n_in,
                              void* d_out, int out_size, void* d_ws, size_t ws_size,
                              hipStream_t stream) {
  const float* x     = (const float*)d_in[0];
  const float* pos   = (const float*)d_in[1];
  const int*   ei    = (const int*)d_in[2];
  const int*   batch = (const int*)d_in[3];
  const float* nw1   = (const float*)d_in[4];
  const float* nb1   = (const float*)d_in[5];
  const float* nw2   = (const float*)d_in[6];
  const float* nb2   = (const float*)d_in[7];
  const float* m1w1  = (const float*)d_in[8];
  const float* m1b1  = (const float*)d_in[9];
  const float* m1w2  = (const float*)d_in[10];
  const float* m1b2  = (const float*)d_in[11];
  const float* m2w1  = (const float*)d_in[12];
  const float* m2b1  = (const float*)d_in[13];
  const float* m2w2  = (const float*)d_in[14];
  const float* m2b2  = (const float*)d_in[15];
  const float* m3w1  = (const float*)d_in[16];
  const float* m3b1  = (const float*)d_in[17];
  const float* m3w2  = (const float*)d_in[18];
  const float* m3b2  = (const float*)d_in[19];
  const float* l1w   = (const float*)d_in[20];
  const float* l1b   = (const float*)d_in[21];
  const float* l2w   = (const float*)d_in[22];
  const float* l2b   = (const float*)d_in[23];

  const int N = in_sizes[0];
  const int E = in_sizes[2] / 2;
  const int L = in_sizes[8] / (256 * 128);

  float* Pagg = (float*)d_ws;                                   // [N,128] f32
  unsigned int* spk = (unsigned int*)(Pagg + (size_t)N * HD);   // [E]
  int*   cnt  = (int*)(spk + E);                                // [N]
  float* invd = (float*)(cnt + N);                              // [N]
  float* Wf   = invd + N;                                       // [L,128,128]
  float* ub   = Wf + (size_t)L * 128 * 128;                     // [L,128]
  float* Wm   = ub + (size_t)L * 128;                           // [L,128,128]
  float* bfold= Wm + (size_t)L * 128 * 128;                     // [L,128]
  unsigned short* hAb = (unsigned short*)(bfold + (size_t)L * 128);  // [N,128]
  unsigned short* Wpk = hAb + (size_t)N * HD;                   // [L,16384]
  float* ybuf = (float*)(Wpk + (size_t)L * 16384);              // [N]
  int*   bsum = (int*)(ybuf + N);                               // [128]
  unsigned short* WnBase = (unsigned short*)(bsum + 128);
  unsigned short* WnInit = WnBase;
  unsigned short* WnW2a[3], *WnCat[3], *WnW2[3];
  unsigned short* planes;
  {
    unsigned short* p = WnBase + 32768;
    for (int l = 0; l < 3; ++l) {
      WnW2a[l] = p; p += 32768;
      WnCat[l] = p; p += 65536;
      WnW2[l]  = p; p += 32768;
    }
    planes = p;
  }
  unsigned short* hH = planes;                 // [N,128]
  unsigned short* hL = hH + (size_t)N * HD;

  hipMemsetAsync(cnt, 0, (size_t)N * sizeof(int), stream);
  hipMemsetAsync(d_out, 0, (size_t)out_size * sizeof(float), stream);

  count_k<<<(E + 255) / 256, 256, 0, stream>>>(ei, cnt, E);
  const int nsb = (N + 511) / 512;
  scanA_k<<<nsb, 512, 0, stream>>>(cnt, bsum, N);
  scanB_k<<<1, 128, 0, stream>>>(bsum, nsb);
  scanC_k<<<nsb, 512, 0, stream>>>(cnt, invd, bsum, N);
  scatter_k<<<(E + 255) / 256, 256, 0, stream>>>(ei, cnt, spk, E);
  fold_all_k<<<dim3(128, L, 2), 128, 0, stream>>>(m3w2, m2w1, m3b2, m2b1,
                                                  m2w2, m1w1, m2b2, Wf, ub, Wm, bfold);
  pack_k<<<dim3(64, L), 256, 0, stream>>>(Wf, Wpk);

  {
    PArgs pa;
    pa.d[0] = {nw2, nullptr, WnInit, 4};
    for (int l = 0; l < L; ++l) {
      pa.d[1 + l * 3] = {m2w1 + (size_t)l * 256 * 128, nullptr, WnW2a[l], 4};
      pa.d[2 + l * 3] = {Wm + (size_t)l * 128 * 128,
                         m1w1 + (size_t)l * 256 * 128 + 128 * 128, WnCat[l], 8};
      pa.d[3 + l * 3] = {m1w2 + (size_t)l * 128 * 128, nullptr, WnW2[l], 4};
    }
    packw_k<<<dim3(128, 1 + L * 3), 256, 0, stream>>>(pa);
  }

  const int gblk = (N + 63) / 64;
  init_k<<<gblk, 256, 0, stream>>>(x, WnInit, nb2, nw1, nb1, hH, hL, WnW2a[0], hAb, N);

  const int nwg = (E + 63) / 64;
  const int nbz = ((nwg - 1) * 32 + 255) / 256;
  for (int l = 0; l < L; ++l) {
    bzero_k<<<nbz, 256, 0, stream>>>(spk, Pagg, nwg);
    edge_k<<<nwg, 256, 0, stream>>>(
        spk, pos, hAb,
        m3w1 + (size_t)l * 3 * 128, m3b1 + (size_t)l * 128,
        Wpk + (size_t)l * 16384, ub + (size_t)l * 128,
        Pagg, E, nwg);
    if (l + 1 < L) {
      layer_k<false><<<gblk, 256, 0, stream>>>(
          Pagg, hH, hL, invd, WnCat[l], m1b1 + (size_t)l * 128,
          bfold + (size_t)l * 128, WnW2[l], m1b2 + (size_t)l * 128,
          WnW2a[l + 1], hH, hL, hAb, N);
    } else {
      layer_k<true><<<gblk, 256, 0, stream>>>(
          Pagg, hH, hL, invd, WnCat[l], m1b1 + (size_t)l * 128,
          bfold + (size_t)l * 128, WnW2[l], m1b2 + (size_t)l * 128,
          nullptr, hH, hL, nullptr, N);
    }
  }

  readout1_k<<<(N + 127) / 128, 256, 0, stream>>>(hH, l1w, l1b, l2w, l2b, ybuf, N);
  readout2_k<<<(N + 2047) / 2048, 256, 0, stream>>>(ybuf, batch, (float*)d_out, N);
}